// Round 1
// baseline (760.947 us; speedup 1.0000x reference)
//
#include <hip/hip_runtime.h>
#include <hip/hip_bf16.h>
#include <stdint.h>

#define NB 4
#define NN 4096
#define DD 128

__device__ __forceinline__ float wave_sum(float v) {
  #pragma unroll
  for (int o = 32; o > 0; o >>= 1) v += __shfl_xor(v, o, 64);
  return v;
}

// ---------------- K1: LayerNorm -> x@w1+b1 -> exact GELU -> h, rnorm ----------
__global__ __launch_bounds__(128) void k_ln_gelu(
    const float* __restrict__ x, const float* __restrict__ ln_g,
    const float* __restrict__ ln_b, const float* __restrict__ w1,
    const float* __restrict__ b1, float* __restrict__ h,
    float* __restrict__ rnorm) {
  int row = blockIdx.x;
  int tid = threadIdx.x;
  __shared__ float v[128];
  __shared__ float red[2];
  float xv = x[(size_t)row * DD + tid];
  float s = wave_sum(xv);
  if ((tid & 63) == 0) red[tid >> 6] = s;
  __syncthreads();
  float mu = (red[0] + red[1]) * (1.0f / 128.0f);
  __syncthreads();
  float d = xv - mu;
  float s2 = wave_sum(d * d);
  if ((tid & 63) == 0) red[tid >> 6] = s2;
  __syncthreads();
  float var = (red[0] + red[1]) * (1.0f / 128.0f);
  float hn = d * (1.0f / sqrtf(var + 1e-5f)) * ln_g[tid] + ln_b[tid];
  v[tid] = hn;
  __syncthreads();
  float acc = b1[tid];
  #pragma unroll 8
  for (int i = 0; i < 128; ++i) acc += v[i] * w1[i * 128 + tid];
  float g = 0.5f * acc * (1.0f + erff(acc * 0.70710678118654752440f));
  h[(size_t)row * 128 + tid] = g;
  float ss = wave_sum(g * g);
  __syncthreads();
  if ((tid & 63) == 0) red[tid >> 6] = ss;
  __syncthreads();
  if (tid == 0) {
    float nrm = sqrtf(red[0] + red[1]);
    rnorm[row] = 1.0f / fmaxf(nrm, 1e-12f);
  }
}

// ---------------- K2: scores tile (64x64), relu, write to chunk scratch -------
#define LSTR 68
__global__ __launch_bounds__(256) void k_scores(
    const float* __restrict__ h, const float* __restrict__ rnorm,
    float* __restrict__ S, int b, int q0) {
  __shared__ float Qs[64 * LSTR];
  __shared__ float Cs[64 * LSTR];
  int tid = threadIdx.x;
  int cbase = blockIdx.x * 64;            // column rows (batch-local)
  int qbase = q0 + blockIdx.y * 64;       // query rows (batch-local)
  const float* hb = h + (size_t)b * NN * 128;
  const float* rb = rnorm + (size_t)b * NN;
  int tx = tid & 15;
  int ty = tid >> 4;

  float acc[4][4];
  #pragma unroll
  for (int r = 0; r < 4; ++r)
    #pragma unroll
    for (int c = 0; c < 4; ++c) acc[r][c] = 0.0f;

  #pragma unroll
  for (int ks = 0; ks < 2; ++ks) {
    // stage 64 rows x 64 cols of each operand, normalized on the fly
    #pragma unroll
    for (int j = 0; j < 4; ++j) {
      int f4 = tid + 256 * j;        // 0..1023
      int r = f4 >> 4;               // 16 float4 per row
      int c4 = f4 & 15;
      float rq = rb[qbase + r];
      float4 q = *(const float4*)(hb + (size_t)(qbase + r) * 128 + ks * 64 + c4 * 4);
      q.x *= rq; q.y *= rq; q.z *= rq; q.w *= rq;
      *(float4*)(&Qs[r * LSTR + c4 * 4]) = q;
      float rc = rb[cbase + r];
      float4 cc = *(const float4*)(hb + (size_t)(cbase + r) * 128 + ks * 64 + c4 * 4);
      cc.x *= rc; cc.y *= rc; cc.z *= rc; cc.w *= rc;
      *(float4*)(&Cs[r * LSTR + c4 * 4]) = cc;
    }
    __syncthreads();
    #pragma unroll 4
    for (int k = 0; k < 64; k += 4) {
      float4 aq[4], ac[4];
      #pragma unroll
      for (int r = 0; r < 4; ++r) aq[r] = *(const float4*)(&Qs[(ty + 16 * r) * LSTR + k]);
      #pragma unroll
      for (int c = 0; c < 4; ++c) ac[c] = *(const float4*)(&Cs[(tx + 16 * c) * LSTR + k]);
      #pragma unroll
      for (int r = 0; r < 4; ++r)
        #pragma unroll
        for (int c = 0; c < 4; ++c)
          acc[r][c] += aq[r].x * ac[c].x + aq[r].y * ac[c].y +
                       aq[r].z * ac[c].z + aq[r].w * ac[c].w;
    }
    __syncthreads();
  }
  int qloc0 = blockIdx.y * 64;  // chunk-local row base
  #pragma unroll
  for (int r = 0; r < 4; ++r)
    #pragma unroll
    for (int c = 0; c < 4; ++c) {
      int qq = qloc0 + ty + 16 * r;
      int mm = cbase + tx + 16 * c;
      S[(size_t)qq * NN + mm] = fmaxf(acc[r][c], 0.0f);
    }
}

// ---------------- K3: exact top-32 per row (1 wave/row), deg, dm12 ------------
__global__ __launch_bounds__(256) void k_topk(
    const float* __restrict__ S, int* __restrict__ nidx,
    float* __restrict__ nval, float* __restrict__ dm12,
    const float* __restrict__ p_log_tau, int b, int q0, int nrows_chunk) {
  int wave = threadIdx.x >> 6;
  int lane = threadIdx.x & 63;
  int rloc = blockIdx.x * 4 + wave;
  if (rloc >= nrows_chunk) return;
  const float* Sr = S + (size_t)rloc * NN;

  unsigned long long k0 = 0, k1 = 0, k2 = 0, k3 = 0, k4 = 0, k5 = 0, k6 = 0, k7 = 0;
  for (int j = 0; j < 16; ++j) {
    int m0 = j * 256 + lane * 4;
    float4 sv = *(const float4*)(Sr + m0);
    #pragma unroll
    for (int t = 0; t < 4; ++t) {
      float sc = (&sv.x)[t];
      unsigned long long key =
          ((unsigned long long)__float_as_uint(sc) << 32) | (unsigned)(4095 - (m0 + t));
      if (key > k7) {
        k7 = key;
        unsigned long long tt;
        if (k7 > k6) { tt = k6; k6 = k7; k7 = tt; }
        if (k6 > k5) { tt = k5; k5 = k6; k6 = tt; }
        if (k5 > k4) { tt = k4; k4 = k5; k5 = tt; }
        if (k4 > k3) { tt = k3; k3 = k4; k4 = tt; }
        if (k3 > k2) { tt = k2; k2 = k3; k3 = tt; }
        if (k2 > k1) { tt = k1; k1 = k2; k2 = tt; }
        if (k1 > k0) { tt = k0; k0 = k1; k1 = tt; }
      }
    }
  }

  float sum = 0.0f;
  int myidx = 4095;
  float myval = 0.0f;
  for (int e = 0; e < 32; ++e) {
    unsigned long long v = k0;
    #pragma unroll
    for (int o = 32; o > 0; o >>= 1) {
      unsigned long long w = __shfl_xor(v, o, 64);
      if (w > v) v = w;
    }
    float val = __uint_as_float((unsigned)(v >> 32));
    int m = 4095 - (int)(v & 0xFFFull);
    if (v != 0ull) {
      unsigned long long ball = __ballot(k0 == v);
      int winner = __ffsll(ball) - 1;
      if (lane == winner) { k0 = k1; k1 = k2; k2 = k3; k3 = k4; k4 = k5; k5 = k6; k6 = k7; k7 = 0; }
    } else { val = 0.0f; m = 4095; }
    sum += val;
    if (lane == e) { myidx = m; myval = val; }
  }
  int grow = b * NN + (q0 + rloc);
  if (lane < 32) {
    nidx[(size_t)grow * 32 + lane] = myidx;
    nval[(size_t)grow * 32 + lane] = myval;
  }
  if (lane == 0) {
    float tau = fmaxf(expf(p_log_tau[0]), 1e-3f);
    float deg = 0.9f * ((sum + 1.0f) / tau) + 0.1f;
    deg = fmaxf(deg, 1e-6f);
    dm12[grow] = 1.0f / sqrtf(deg);
  }
}

// ---------------- K4: T1 = Ahat @ h (sparse gather) ---------------------------
__global__ __launch_bounds__(128) void k_cheb1(
    const float* __restrict__ h, const int* __restrict__ nidx,
    const float* __restrict__ nval, const float* __restrict__ dm12,
    const float* __restrict__ p_log_tau, float* __restrict__ T1) {
  int row = blockIdx.x;
  int b = row >> 12;
  int tid = threadIdx.x;
  __shared__ float cj[32];
  __shared__ int mj[32];
  __shared__ float cdsh;
  float tau = fmaxf(expf(p_log_tau[0]), 1e-3f);
  float scale = 0.9f / tau;
  float dn = dm12[row];
  if (tid < 32) {
    int m = nidx[(size_t)row * 32 + tid];
    cj[tid] = scale * nval[(size_t)row * 32 + tid] * dn * dm12[b * NN + m];
    mj[tid] = m;
  }
  if (tid == 0) cdsh = (scale + 0.1f) * dn * dn;
  __syncthreads();
  const float* hb = h + (size_t)b * NN * 128;
  float acc = cdsh * h[(size_t)row * 128 + tid];
  #pragma unroll 8
  for (int j = 0; j < 32; ++j)
    acc += cj[j] * hb[(size_t)mj[j] * 128 + tid];
  T1[(size_t)row * 128 + tid] = acc;
}

// ---------------- K5: T2, y = hcat@w2 + b2, out = x + tanh(gate)*y ------------
__global__ __launch_bounds__(256) void k_cheb2_out(
    const float* __restrict__ x, const float* __restrict__ h,
    const float* __restrict__ T1, const int* __restrict__ nidx,
    const float* __restrict__ nval, const float* __restrict__ dm12,
    const float* __restrict__ w2, const float* __restrict__ b2,
    const float* __restrict__ p_log_tau, const float* __restrict__ p_gate,
    float* __restrict__ out) {
  int rr = threadIdx.x >> 7;
  int f = threadIdx.x & 127;
  int row = blockIdx.x * 2 + rr;
  int b = row >> 12;
  __shared__ float T0s[2][128], T1s[2][128], T2s[2][128];
  __shared__ float cj[2][32];
  __shared__ int mj[2][32];
  __shared__ float cds[2];
  float tau = fmaxf(expf(p_log_tau[0]), 1e-3f);
  float scale = 0.9f / tau;
  float dn = dm12[row];
  if (f < 32) {
    int m = nidx[(size_t)row * 32 + f];
    cj[rr][f] = scale * nval[(size_t)row * 32 + f] * dn * dm12[b * NN + m];
    mj[rr][f] = m;
  }
  if (f == 0) cds[rr] = (scale + 0.1f) * dn * dn;
  float t0 = h[(size_t)row * 128 + f];
  float t1 = T1[(size_t)row * 128 + f];
  T0s[rr][f] = t0;
  T1s[rr][f] = t1;
  __syncthreads();
  const float* T1b = T1 + (size_t)b * NN * 128;
  float a = cds[rr] * t1;
  #pragma unroll 8
  for (int j = 0; j < 32; ++j)
    a += cj[rr][j] * T1b[(size_t)mj[rr][j] * 128 + f];
  float t2 = 2.0f * a - t0;
  T2s[rr][f] = t2;
  __syncthreads();
  float y = b2[f];
  #pragma unroll 4
  for (int k = 0; k < 128; ++k) {
    y += T0s[rr][k] * w2[k * 128 + f];
    y += T1s[rr][k] * w2[(128 + k) * 128 + f];
    y += T2s[rr][k] * w2[(256 + k) * 128 + f];
  }
  float tg = tanhf(p_gate[0]);
  out[(size_t)row * 128 + f] = x[(size_t)row * 128 + f] + tg * y;
}

extern "C" void kernel_launch(void* const* d_in, const int* in_sizes, int n_in,
                              void* d_out, int out_size, void* d_ws, size_t ws_size,
                              hipStream_t stream) {
  const float* x = (const float*)d_in[0];
  const float* ln_g = (const float*)d_in[1];
  const float* ln_b = (const float*)d_in[2];
  const float* w1 = (const float*)d_in[3];
  const float* b1 = (const float*)d_in[4];
  const float* w2 = (const float*)d_in[5];
  const float* b2 = (const float*)d_in[6];
  const float* p_log_tau = (const float*)d_in[7];
  const float* p_gate = (const float*)d_in[8];
  float* out = (float*)d_out;

  char* ws = (char*)d_ws;
  size_t off = 0;
  auto alloc = [&](size_t bytes) -> void* {
    off = (off + 255) & ~(size_t)255;
    void* p = ws + off;
    off += bytes;
    return p;
  };
  float* h = (float*)alloc((size_t)NB * NN * 128 * 4);
  float* rnorm = (float*)alloc((size_t)NB * NN * 4);
  float* T1 = (float*)alloc((size_t)NB * NN * 128 * 4);
  int* nidx = (int*)alloc((size_t)NB * NN * 32 * 4);
  float* nval = (float*)alloc((size_t)NB * NN * 32 * 4);
  float* dm12 = (float*)alloc((size_t)NB * NN * 4);
  off = (off + 255) & ~(size_t)255;
  size_t avail = (ws_size > off) ? (ws_size - off) : 0;
  long long Rll = (long long)(avail / ((size_t)NN * 4));
  int R = (int)((Rll > NN) ? NN : Rll);
  R = (R / 64) * 64;
  if (R > NN) R = NN;
  if (R < 64) R = 64;  // minimum viable chunk
  float* S = (float*)(ws + off);

  k_ln_gelu<<<NB * NN, 128, 0, stream>>>(x, ln_g, ln_b, w1, b1, h, rnorm);

  for (int b = 0; b < NB; ++b) {
    for (int q0 = 0; q0 < NN; q0 += R) {
      int rc = (NN - q0 < R) ? (NN - q0) : R;
      dim3 g(NN / 64, rc / 64);
      k_scores<<<g, 256, 0, stream>>>(h, rnorm, S, b, q0);
      k_topk<<<(rc + 3) / 4, 256, 0, stream>>>(S, nidx, nval, dm12, p_log_tau, b, q0, rc);
    }
  }

  k_cheb1<<<NB * NN, 128, 0, stream>>>(h, nidx, nval, dm12, p_log_tau, T1);
  k_cheb2_out<<<NB * NN / 2, 256, 0, stream>>>(x, h, T1, nidx, nval, dm12, w2, b2,
                                               p_log_tau, p_gate, out);
}

// Round 2
// 511.398 us; speedup vs baseline: 1.4880x; 1.4880x over previous
//
#include <hip/hip_runtime.h>
#include <hip/hip_bf16.h>
#include <stdint.h>

#define NB 4
#define NN 4096

using f16x8 = __attribute__((ext_vector_type(8))) _Float16;
using f32x4 = __attribute__((ext_vector_type(4))) float;

__device__ __forceinline__ float wave_sum(float v) {
  #pragma unroll
  for (int o = 32; o > 0; o >>= 1) v += __shfl_xor(v, o, 64);
  return v;
}

// ---- K1: LayerNorm -> x@w1+b1 -> exact GELU -> h (fp32), hn16 (normalized fp16,
//      pre-swizzled 16B chunks: logical chunk c stored at c ^ (row&7)) ----------
__global__ __launch_bounds__(128) void k_ln_gelu(
    const float* __restrict__ x, const float* __restrict__ ln_g,
    const float* __restrict__ ln_b, const float* __restrict__ w1,
    const float* __restrict__ b1, float* __restrict__ h,
    _Float16* __restrict__ hn16) {
  int row = blockIdx.x;
  int tid = threadIdx.x;
  __shared__ float v[128];
  __shared__ float red[2];
  float xv = x[(size_t)row * 128 + tid];
  float s = wave_sum(xv);
  if ((tid & 63) == 0) red[tid >> 6] = s;
  __syncthreads();
  float mu = (red[0] + red[1]) * (1.0f / 128.0f);
  __syncthreads();
  float d = xv - mu;
  float s2 = wave_sum(d * d);
  if ((tid & 63) == 0) red[tid >> 6] = s2;
  __syncthreads();
  float var = (red[0] + red[1]) * (1.0f / 128.0f);
  float hn = d * (1.0f / sqrtf(var + 1e-5f)) * ln_g[tid] + ln_b[tid];
  v[tid] = hn;
  __syncthreads();
  float acc = b1[tid];
  #pragma unroll 8
  for (int i = 0; i < 128; ++i) acc += v[i] * w1[i * 128 + tid];
  float g = 0.5f * acc * (1.0f + erff(acc * 0.70710678118654752440f));
  h[(size_t)row * 128 + tid] = g;
  float ss = wave_sum(g * g);
  __syncthreads();          // everyone done reading v[] for the matmul
  v[tid] = g;
  if ((tid & 63) == 0) red[tid >> 6] = ss;
  __syncthreads();
  float rinv = 1.0f / fmaxf(sqrtf(red[0] + red[1]), 1e-12f);
  if (tid < 16) {
    union { _Float16 hh[8]; uint4 u; } pk;
    #pragma unroll
    for (int j = 0; j < 8; ++j) pk.hh[j] = (_Float16)(v[tid * 8 + j] * rinv);
    int slot = tid ^ (row & 7);
    *(uint4*)(hn16 + (size_t)row * 128 + slot * 8) = pk.u;
  }
}

// ---- K2: scores via fp16 MFMA. 128x128 tile, 4 waves (2x2), K=128 one shot. ---
__global__ __launch_bounds__(256) void k_scores(
    const _Float16* __restrict__ hn16, float* __restrict__ S, int b, int q0) {
  __shared__ _Float16 Qs[128 * 128];
  __shared__ _Float16 Cs[128 * 128];
  int tid = threadIdx.x;
  int lane = tid & 63;
  int wv = tid >> 6;
  int wr = wv >> 1, wc = wv & 1;
  int cbase = blockIdx.x * 128;
  int qbase = q0 + blockIdx.y * 128;
  const _Float16* hq = hn16 + (size_t)b * NN * 128 + (size_t)qbase * 128;
  const _Float16* hc = hn16 + (size_t)b * NN * 128 + (size_t)cbase * 128;
  #pragma unroll
  for (int i = 0; i < 8; ++i) {
    int idx = tid + 256 * i;  // 16B-chunk index 0..2047 (global is pre-swizzled)
    __builtin_amdgcn_global_load_lds(
        (const __attribute__((address_space(1))) void*)(hq + (size_t)idx * 8),
        (__attribute__((address_space(3))) void*)(Qs + (size_t)idx * 8), 16, 0, 0);
    __builtin_amdgcn_global_load_lds(
        (const __attribute__((address_space(1))) void*)(hc + (size_t)idx * 8),
        (__attribute__((address_space(3))) void*)(Cs + (size_t)idx * 8), 16, 0, 0);
  }
  asm volatile("s_waitcnt vmcnt(0)" ::: "memory");
  __syncthreads();

  f32x4 acc[4][4];
  #pragma unroll
  for (int i = 0; i < 4; ++i)
    #pragma unroll
    for (int j = 0; j < 4; ++j) acc[i][j] = (f32x4){0.f, 0.f, 0.f, 0.f};

  int rl = lane & 15;
  int kg = lane >> 4;
  #pragma unroll
  for (int kk = 0; kk < 4; ++kk) {
    int cL = kk * 4 + kg;  // logical 16B chunk within row
    f16x8 a[4], bb[4];
    #pragma unroll
    for (int i = 0; i < 4; ++i) {
      int r = wr * 64 + i * 16 + rl;
      a[i] = *(const f16x8*)(Qs + r * 128 + (cL ^ (r & 7)) * 8);
    }
    #pragma unroll
    for (int j = 0; j < 4; ++j) {
      int r = wc * 64 + j * 16 + rl;
      bb[j] = *(const f16x8*)(Cs + r * 128 + (cL ^ (r & 7)) * 8);
    }
    #pragma unroll
    for (int i = 0; i < 4; ++i)
      #pragma unroll
      for (int j = 0; j < 4; ++j)
        acc[i][j] = __builtin_amdgcn_mfma_f32_16x16x32_f16(a[i], bb[j], acc[i][j], 0, 0, 0);
  }
  int qloc0 = blockIdx.y * 128;
  #pragma unroll
  for (int i = 0; i < 4; ++i)
    #pragma unroll
    for (int j = 0; j < 4; ++j) {
      int q = qloc0 + wr * 64 + i * 16 + kg * 4;
      int m = cbase + wc * 64 + j * 16 + rl;
      #pragma unroll
      for (int rg = 0; rg < 4; ++rg)
        S[(size_t)(q + rg) * NN + m] = fmaxf(acc[i][j][rg], 0.0f);
    }
}

// ---- K3: exact top-32 per row (1 wave/row), deg, dm12 -------------------------
__global__ __launch_bounds__(256) void k_topk(
    const float* __restrict__ S, int* __restrict__ nidx,
    float* __restrict__ nval, float* __restrict__ dm12,
    const float* __restrict__ p_log_tau, int b, int q0, int nrows_chunk) {
  int wave = threadIdx.x >> 6;
  int lane = threadIdx.x & 63;
  int rloc = blockIdx.x * 4 + wave;
  if (rloc >= nrows_chunk) return;
  const float* Sr = S + (size_t)rloc * NN;

  unsigned long long k0 = 0, k1 = 0, k2 = 0, k3 = 0, k4 = 0, k5 = 0, k6 = 0, k7 = 0;
  for (int j = 0; j < 16; ++j) {
    int m0 = j * 256 + lane * 4;
    float4 sv = *(const float4*)(Sr + m0);
    #pragma unroll
    for (int t = 0; t < 4; ++t) {
      float sc = (&sv.x)[t];
      unsigned long long key =
          ((unsigned long long)__float_as_uint(sc) << 32) | (unsigned)(4095 - (m0 + t));
      if (key > k7) {
        k7 = key;
        unsigned long long tt;
        if (k7 > k6) { tt = k6; k6 = k7; k7 = tt; }
        if (k6 > k5) { tt = k5; k5 = k6; k6 = tt; }
        if (k5 > k4) { tt = k4; k4 = k5; k5 = tt; }
        if (k4 > k3) { tt = k3; k3 = k4; k4 = tt; }
        if (k3 > k2) { tt = k2; k2 = k3; k3 = tt; }
        if (k2 > k1) { tt = k1; k1 = k2; k2 = tt; }
        if (k1 > k0) { tt = k0; k0 = k1; k1 = tt; }
      }
    }
  }

  float sum = 0.0f;
  int myidx = 4095;
  float myval = 0.0f;
  for (int e = 0; e < 32; ++e) {
    unsigned long long v = k0;
    #pragma unroll
    for (int o = 32; o > 0; o >>= 1) {
      unsigned long long w = __shfl_xor(v, o, 64);
      if (w > v) v = w;
    }
    float val = __uint_as_float((unsigned)(v >> 32));
    int m = 4095 - (int)(v & 0xFFFull);
    if (v != 0ull) {
      unsigned long long ball = __ballot(k0 == v);
      int winner = __ffsll(ball) - 1;
      if (lane == winner) { k0 = k1; k1 = k2; k2 = k3; k3 = k4; k4 = k5; k5 = k6; k6 = k7; k7 = 0; }
    } else { val = 0.0f; m = 4095; }
    sum += val;
    if (lane == e) { myidx = m; myval = val; }
  }
  int grow = b * NN + (q0 + rloc);
  if (lane < 32) {
    nidx[(size_t)grow * 32 + lane] = myidx;
    nval[(size_t)grow * 32 + lane] = myval;
  }
  if (lane == 0) {
    float tau = fmaxf(expf(p_log_tau[0]), 1e-3f);
    float deg = 0.9f * ((sum + 1.0f) / tau) + 0.1f;
    deg = fmaxf(deg, 1e-6f);
    dm12[grow] = 1.0f / sqrtf(deg);
  }
}

// ---- K4: T1 = Ahat @ h (sparse gather) ----------------------------------------
__global__ __launch_bounds__(128) void k_cheb1(
    const float* __restrict__ h, const int* __restrict__ nidx,
    const float* __restrict__ nval, const float* __restrict__ dm12,
    const float* __restrict__ p_log_tau, float* __restrict__ T1) {
  int row = blockIdx.x;
  int b = row >> 12;
  int tid = threadIdx.x;
  __shared__ float cj[32];
  __shared__ int mj[32];
  __shared__ float cdsh;
  float tau = fmaxf(expf(p_log_tau[0]), 1e-3f);
  float scale = 0.9f / tau;
  float dn = dm12[row];
  if (tid < 32) {
    int m = nidx[(size_t)row * 32 + tid];
    cj[tid] = scale * nval[(size_t)row * 32 + tid] * dn * dm12[b * NN + m];
    mj[tid] = m;
  }
  if (tid == 0) cdsh = (scale + 0.1f) * dn * dn;
  __syncthreads();
  const float* hb = h + (size_t)b * NN * 128;
  float acc = cdsh * h[(size_t)row * 128 + tid];
  #pragma unroll 8
  for (int j = 0; j < 32; ++j)
    acc += cj[j] * hb[(size_t)mj[j] * 128 + tid];
  T1[(size_t)row * 128 + tid] = acc;
}

// ---- K5: T2 = 2*Ahat@T1 - T0 --------------------------------------------------
__global__ __launch_bounds__(128) void k_cheb2(
    const float* __restrict__ h, const float* __restrict__ T1,
    const int* __restrict__ nidx, const float* __restrict__ nval,
    const float* __restrict__ dm12, const float* __restrict__ p_log_tau,
    float* __restrict__ T2) {
  int row = blockIdx.x;
  int b = row >> 12;
  int tid = threadIdx.x;
  __shared__ float cj[32];
  __shared__ int mj[32];
  __shared__ float cdsh;
  float tau = fmaxf(expf(p_log_tau[0]), 1e-3f);
  float scale = 0.9f / tau;
  float dn = dm12[row];
  if (tid < 32) {
    int m = nidx[(size_t)row * 32 + tid];
    cj[tid] = scale * nval[(size_t)row * 32 + tid] * dn * dm12[b * NN + m];
    mj[tid] = m;
  }
  if (tid == 0) cdsh = (scale + 0.1f) * dn * dn;
  __syncthreads();
  const float* T1b = T1 + (size_t)b * NN * 128;
  float a = cdsh * T1[(size_t)row * 128 + tid];
  #pragma unroll 8
  for (int j = 0; j < 32; ++j)
    a += cj[j] * T1b[(size_t)mj[j] * 128 + tid];
  T2[(size_t)row * 128 + tid] = 2.0f * a - h[(size_t)row * 128 + tid];
}

// ---- K6: out = x + tanh(gate) * ([h|T1|T2] @ w2 + b2); tiled fp32 GEMM --------
__global__ __launch_bounds__(256) void k_out(
    const float* __restrict__ x, const float* __restrict__ h,
    const float* __restrict__ T1, const float* __restrict__ T2,
    const float* __restrict__ w2, const float* __restrict__ b2,
    const float* __restrict__ p_gate, float* __restrict__ out) {
  __shared__ float As[64][68];    // 64 rows x 64 k
  __shared__ float Bs[64][132];   // 64 k x 128 cols
  int tid = threadIdx.x;
  int tx = tid & 15, ty = tid >> 4;
  int rbase = blockIdx.x * 64;
  float acc[4][8];
  #pragma unroll
  for (int i = 0; i < 4; ++i)
    #pragma unroll
    for (int j = 0; j < 8; ++j) acc[i][j] = 0.0f;

  for (int kc = 0; kc < 6; ++kc) {
    const float* src = kc < 2 ? h : (kc < 4 ? T1 : T2);
    int ko = (kc & 1) * 64;
    #pragma unroll
    for (int i = 0; i < 4; ++i) {       // 64x64 floats = 1024 float4
      int idx = tid + 256 * i;
      int r = idx >> 4, c = idx & 15;
      *(float4*)&As[r][c * 4] = *(const float4*)(src + (size_t)(rbase + r) * 128 + ko + c * 4);
    }
    #pragma unroll
    for (int i = 0; i < 8; ++i) {       // 64x128 floats = 2048 float4
      int idx = tid + 256 * i;
      int r = idx >> 5, c = idx & 31;
      *(float4*)&Bs[r][c * 4] = *(const float4*)(w2 + (size_t)(kc * 64 + r) * 128 + c * 4);
    }
    __syncthreads();
    #pragma unroll 2
    for (int k = 0; k < 64; ++k) {
      float av[4], bv[8];
      #pragma unroll
      for (int i = 0; i < 4; ++i) av[i] = As[ty + 16 * i][k];
      #pragma unroll
      for (int j = 0; j < 8; ++j) bv[j] = Bs[k][tx + 16 * j];
      #pragma unroll
      for (int i = 0; i < 4; ++i)
        #pragma unroll
        for (int j = 0; j < 8; ++j) acc[i][j] += av[i] * bv[j];
    }
    __syncthreads();
  }
  float tg = tanhf(p_gate[0]);
  #pragma unroll
  for (int i = 0; i < 4; ++i) {
    int row = rbase + ty + 16 * i;
    #pragma unroll
    for (int j = 0; j < 8; ++j) {
      int col = tx + 16 * j;
      out[(size_t)row * 128 + col] =
          x[(size_t)row * 128 + col] + tg * (acc[i][j] + b2[col]);
    }
  }
}

extern "C" void kernel_launch(void* const* d_in, const int* in_sizes, int n_in,
                              void* d_out, int out_size, void* d_ws, size_t ws_size,
                              hipStream_t stream) {
  (void)in_sizes; (void)n_in; (void)out_size;
  const float* x = (const float*)d_in[0];
  const float* ln_g = (const float*)d_in[1];
  const float* ln_b = (const float*)d_in[2];
  const float* w1 = (const float*)d_in[3];
  const float* b1 = (const float*)d_in[4];
  const float* w2 = (const float*)d_in[5];
  const float* b2 = (const float*)d_in[6];
  const float* p_log_tau = (const float*)d_in[7];
  const float* p_gate = (const float*)d_in[8];
  float* out = (float*)d_out;

  char* ws = (char*)d_ws;
  size_t off = 0;
  auto alloc = [&](size_t bytes) -> void* {
    off = (off + 255) & ~(size_t)255;
    void* p = ws + off;
    off += bytes;
    return p;
  };
  float* h = (float*)alloc((size_t)NB * NN * 128 * 4);
  _Float16* hn16 = (_Float16*)alloc((size_t)NB * NN * 128 * 2);
  float* T1 = (float*)alloc((size_t)NB * NN * 128 * 4);
  float* T2 = (float*)alloc((size_t)NB * NN * 128 * 4);
  int* nidx = (int*)alloc((size_t)NB * NN * 32 * 4);
  float* nval = (float*)alloc((size_t)NB * NN * 32 * 4);
  float* dm12 = (float*)alloc((size_t)NB * NN * 4);
  off = (off + 255) & ~(size_t)255;
  size_t avail = (ws_size > off) ? (ws_size - off) : 0;
  long long Rll = (long long)(avail / ((size_t)NN * 4));
  int R = (int)((Rll > NN) ? NN : Rll);
  R = (R / 128) * 128;
  if (R > NN) R = NN;
  if (R < 128) R = 128;  // minimum viable chunk
  float* S = (float*)(ws + off);

  k_ln_gelu<<<NB * NN, 128, 0, stream>>>(x, ln_g, ln_b, w1, b1, h, hn16);

  for (int b = 0; b < NB; ++b) {
    for (int q0 = 0; q0 < NN; q0 += R) {
      int rc = (NN - q0 < R) ? (NN - q0) : R;
      dim3 g(NN / 128, rc / 128);
      k_scores<<<g, 256, 0, stream>>>(hn16, S, b, q0);
      k_topk<<<(rc + 3) / 4, 256, 0, stream>>>(S, nidx, nval, dm12, p_log_tau, b, q0, rc);
    }
  }

  k_cheb1<<<NB * NN, 128, 0, stream>>>(h, nidx, nval, dm12, p_log_tau, T1);
  k_cheb2<<<NB * NN, 128, 0, stream>>>(h, T1, nidx, nval, dm12, p_log_tau, T2);
  k_out<<<NB * NN / 64, 256, 0, stream>>>(x, h, T1, T2, w2, b2, p_gate, out);
}

// Round 3
// 254.872 us; speedup vs baseline: 2.9856x; 2.0065x over previous
//
#include <hip/hip_runtime.h>
#include <hip/hip_bf16.h>
#include <stdint.h>

#define NB 4
#define NN 4096

using f16x8 = __attribute__((ext_vector_type(8))) _Float16;
using f32x4 = __attribute__((ext_vector_type(4))) float;

__device__ __forceinline__ float wave_sum(float v) {
  #pragma unroll
  for (int o = 32; o > 0; o >>= 1) v += __shfl_xor(v, o, 64);
  return v;
}
__device__ __forceinline__ float h2f_bits(unsigned hb) {
  unsigned short us = (unsigned short)hb;
  _Float16 hf;
  __builtin_memcpy(&hf, &us, 2);
  return (float)hf;
}
__device__ __forceinline__ unsigned short f2h_bits(float f) {
  _Float16 hf = (_Float16)f;
  unsigned short us;
  __builtin_memcpy(&us, &hf, 2);
  return us;
}

// ---- k_prep: w1t16[n][k] = fp16(w1[k][n]), 16B chunks pre-swizzled c^=n&7 ----
__global__ __launch_bounds__(128) void k_prep(const float* __restrict__ w1,
                                              _Float16* __restrict__ w1t16) {
  int n = blockIdx.x;
  int k = threadIdx.x;
  __shared__ _Float16 v16[128];
  v16[k] = (_Float16)w1[(size_t)k * 128 + n];
  __syncthreads();
  if (k < 16) {
    union { _Float16 hh[8]; uint4 u; } pk;
    #pragma unroll
    for (int j = 0; j < 8; ++j) pk.hh[j] = v16[k * 8 + j];
    *(uint4*)(w1t16 + (size_t)n * 128 + (size_t)(k ^ (n & 7)) * 8) = pk.u;
  }
}

// ---- k0_ln: LayerNorm -> ln16 (fp16, swizzled 16B chunks) --------------------
__global__ __launch_bounds__(128) void k0_ln(
    const float* __restrict__ x, const float* __restrict__ ln_g,
    const float* __restrict__ ln_b, _Float16* __restrict__ ln16) {
  int tid = threadIdx.x;
  float gg = ln_g[tid], bb = ln_b[tid];
  __shared__ float red[2];
  __shared__ float v[128];
  for (int rr = 0; rr < 8; ++rr) {
    int row = blockIdx.x * 8 + rr;
    float xv = x[(size_t)row * 128 + tid];
    float s = wave_sum(xv);
    if ((tid & 63) == 0) red[tid >> 6] = s;
    __syncthreads();
    float mu = (red[0] + red[1]) * (1.0f / 128.0f);
    __syncthreads();
    float d = xv - mu;
    float s2 = wave_sum(d * d);
    if ((tid & 63) == 0) red[tid >> 6] = s2;
    __syncthreads();
    float var = (red[0] + red[1]) * (1.0f / 128.0f);
    float hn = d * (1.0f / sqrtf(var + 1e-5f)) * gg + bb;
    v[tid] = hn;
    __syncthreads();
    if (tid < 16) {
      union { _Float16 hh[8]; uint4 u; } pk;
      #pragma unroll
      for (int j = 0; j < 8; ++j) pk.hh[j] = (_Float16)v[tid * 8 + j];
      *(uint4*)(ln16 + (size_t)row * 128 + (size_t)(tid ^ (row & 7)) * 8) = pk.u;
    }
    __syncthreads();
  }
}

// ---- k1_mfma: h = GELU(ln @ w1 + b1) via fp16 MFMA, fp32 out -----------------
__global__ __launch_bounds__(256) void k1_mfma(
    const _Float16* __restrict__ ln16, const _Float16* __restrict__ w1t16,
    const float* __restrict__ b1, float* __restrict__ h) {
  __shared__ _Float16 As[64 * 128];   // 16KB
  __shared__ _Float16 Bs[128 * 128];  // 32KB
  int tid = threadIdx.x;
  int lane = tid & 63;
  int wv = tid >> 6;
  int rbase = blockIdx.x * 64;
  #pragma unroll
  for (int i = 0; i < 4; ++i) {
    int idx = tid + 256 * i;
    __builtin_amdgcn_global_load_lds(
        (const __attribute__((address_space(1))) void*)(ln16 + (size_t)rbase * 128 + (size_t)idx * 8),
        (__attribute__((address_space(3))) void*)(As + (size_t)idx * 8), 16, 0, 0);
  }
  #pragma unroll
  for (int i = 0; i < 8; ++i) {
    int idx = tid + 256 * i;
    __builtin_amdgcn_global_load_lds(
        (const __attribute__((address_space(1))) void*)(w1t16 + (size_t)idx * 8),
        (__attribute__((address_space(3))) void*)(Bs + (size_t)idx * 8), 16, 0, 0);
  }
  asm volatile("s_waitcnt vmcnt(0)" ::: "memory");
  __syncthreads();

  int rl = lane & 15, kg = lane >> 4;
  f32x4 acc[8];
  #pragma unroll
  for (int j = 0; j < 8; ++j) acc[j] = (f32x4){0.f, 0.f, 0.f, 0.f};
  #pragma unroll
  for (int kk = 0; kk < 4; ++kk) {
    int cL = kk * 4 + kg;
    int r = wv * 16 + rl;
    f16x8 a = *(const f16x8*)(As + r * 128 + (cL ^ (r & 7)) * 8);
    #pragma unroll
    for (int j = 0; j < 8; ++j) {
      int n = j * 16 + rl;
      f16x8 bf = *(const f16x8*)(Bs + n * 128 + (cL ^ (n & 7)) * 8);
      acc[j] = __builtin_amdgcn_mfma_f32_16x16x32_f16(a, bf, acc[j], 0, 0, 0);
    }
  }
  #pragma unroll
  for (int j = 0; j < 8; ++j) {
    int col = j * 16 + rl;
    float bv = b1[col];
    #pragma unroll
    for (int rg = 0; rg < 4; ++rg) {
      int row = rbase + wv * 16 + kg * 4 + rg;
      float z = acc[j][rg] + bv;
      float g = 0.5f * z * (1.0f + erff(z * 0.70710678118654752440f));
      h[(size_t)row * 128 + col] = g;
    }
  }
}

// ---- k_pack: hn16 = fp16(h / ||h||), swizzled 16B chunks ---------------------
__global__ __launch_bounds__(256) void k_pack(const float* __restrict__ h,
                                              _Float16* __restrict__ hn16) {
  int tid = threadIdx.x;
  int rh = tid >> 7, t = tid & 127;
  int row = blockIdx.x * 2 + rh;
  __shared__ float red[4];
  __shared__ float v[2][128];
  float hv = h[(size_t)row * 128 + t];
  float ss = wave_sum(hv * hv);
  if ((tid & 63) == 0) red[tid >> 6] = ss;
  __syncthreads();
  float rinv = 1.0f / fmaxf(sqrtf(red[rh * 2] + red[rh * 2 + 1]), 1e-12f);
  v[rh][t] = hv * rinv;
  __syncthreads();
  if (t < 16) {
    union { _Float16 hh[8]; uint4 u; } pk;
    #pragma unroll
    for (int j = 0; j < 8; ++j) pk.hh[j] = (_Float16)v[rh][t * 8 + j];
    *(uint4*)(hn16 + (size_t)row * 128 + (size_t)(t ^ (row & 7)) * 8) = pk.u;
  }
}

// ---- k_scores: fp16 MFMA 128x128 tile, relu, fp16 store ----------------------
__global__ __launch_bounds__(256) void k_scores(
    const _Float16* __restrict__ hn16, unsigned short* __restrict__ S, int b, int q0) {
  __shared__ _Float16 Qs[128 * 128];
  __shared__ _Float16 Cs[128 * 128];
  int tid = threadIdx.x;
  int lane = tid & 63;
  int wv = tid >> 6;
  int wr = wv >> 1, wc = wv & 1;
  int cbase = blockIdx.x * 128;
  int qbase = q0 + blockIdx.y * 128;
  const _Float16* hq = hn16 + (size_t)b * NN * 128 + (size_t)qbase * 128;
  const _Float16* hc = hn16 + (size_t)b * NN * 128 + (size_t)cbase * 128;
  #pragma unroll
  for (int i = 0; i < 8; ++i) {
    int idx = tid + 256 * i;
    __builtin_amdgcn_global_load_lds(
        (const __attribute__((address_space(1))) void*)(hq + (size_t)idx * 8),
        (__attribute__((address_space(3))) void*)(Qs + (size_t)idx * 8), 16, 0, 0);
    __builtin_amdgcn_global_load_lds(
        (const __attribute__((address_space(1))) void*)(hc + (size_t)idx * 8),
        (__attribute__((address_space(3))) void*)(Cs + (size_t)idx * 8), 16, 0, 0);
  }
  asm volatile("s_waitcnt vmcnt(0)" ::: "memory");
  __syncthreads();

  f32x4 acc[4][4];
  #pragma unroll
  for (int i = 0; i < 4; ++i)
    #pragma unroll
    for (int j = 0; j < 4; ++j) acc[i][j] = (f32x4){0.f, 0.f, 0.f, 0.f};

  int rl = lane & 15;
  int kg = lane >> 4;
  #pragma unroll
  for (int kk = 0; kk < 4; ++kk) {
    int cL = kk * 4 + kg;
    f16x8 a[4], bb[4];
    #pragma unroll
    for (int i = 0; i < 4; ++i) {
      int r = wr * 64 + i * 16 + rl;
      a[i] = *(const f16x8*)(Qs + r * 128 + (cL ^ (r & 7)) * 8);
    }
    #pragma unroll
    for (int j = 0; j < 4; ++j) {
      int r = wc * 64 + j * 16 + rl;
      bb[j] = *(const f16x8*)(Cs + r * 128 + (cL ^ (r & 7)) * 8);
    }
    #pragma unroll
    for (int i = 0; i < 4; ++i)
      #pragma unroll
      for (int j = 0; j < 4; ++j)
        acc[i][j] = __builtin_amdgcn_mfma_f32_16x16x32_f16(a[i], bb[j], acc[i][j], 0, 0, 0);
  }
  int qloc0 = blockIdx.y * 128;
  #pragma unroll
  for (int i = 0; i < 4; ++i)
    #pragma unroll
    for (int j = 0; j < 4; ++j) {
      int q = qloc0 + wr * 64 + i * 16 + kg * 4;
      int m = cbase + wc * 64 + j * 16 + rl;
      #pragma unroll
      for (int rg = 0; rg < 4; ++rg)
        S[(size_t)(q + rg) * NN + m] = f2h_bits(fmaxf(acc[i][j][rg], 0.0f));
    }
}

// ---- k_topk v2: 1 wave/row, fp16 S, u32 keys, prefetched, branchless ---------
__global__ __launch_bounds__(256) void k_topk(
    const unsigned short* __restrict__ S, int* __restrict__ nidx,
    float* __restrict__ nval, float* __restrict__ dm12,
    const float* __restrict__ p_log_tau, int b, int q0, int nrows) {
  int wave = threadIdx.x >> 6;
  int lane = threadIdx.x & 63;
  int rloc = blockIdx.x * 4 + wave;
  if (rloc >= nrows) return;
  const unsigned short* Sr = S + (size_t)rloc * NN;
  uint4 ld[8];
  #pragma unroll
  for (int j = 0; j < 8; ++j)
    ld[j] = *(const uint4*)(Sr + j * 512 + lane * 8);

  unsigned l0 = 0, l1 = 0, l2 = 0, l3 = 0, l4 = 0, l5 = 0, l6 = 0, l7 = 0;
  #pragma unroll
  for (int j = 0; j < 8; ++j) {
    unsigned u[4] = {ld[j].x, ld[j].y, ld[j].z, ld[j].w};
    int cbase = j * 512 + lane * 8;
    #pragma unroll
    for (int t = 0; t < 4; ++t) {
      unsigned keyA = (u[t] << 16) | (unsigned)(4095 - (cbase + 2 * t));
      unsigned keyB = (u[t] & 0xFFFF0000u) | (unsigned)(4095 - (cbase + 2 * t + 1));
      unsigned c, tm;
      c = keyA;
      tm = max(l0, c); c = min(l0, c); l0 = tm;
      tm = max(l1, c); c = min(l1, c); l1 = tm;
      tm = max(l2, c); c = min(l2, c); l2 = tm;
      tm = max(l3, c); c = min(l3, c); l3 = tm;
      tm = max(l4, c); c = min(l4, c); l4 = tm;
      tm = max(l5, c); c = min(l5, c); l5 = tm;
      tm = max(l6, c); c = min(l6, c); l6 = tm;
      l7 = max(l7, c);
      c = keyB;
      tm = max(l0, c); c = min(l0, c); l0 = tm;
      tm = max(l1, c); c = min(l1, c); l1 = tm;
      tm = max(l2, c); c = min(l2, c); l2 = tm;
      tm = max(l3, c); c = min(l3, c); l3 = tm;
      tm = max(l4, c); c = min(l4, c); l4 = tm;
      tm = max(l5, c); c = min(l5, c); l5 = tm;
      tm = max(l6, c); c = min(l6, c); l6 = tm;
      l7 = max(l7, c);
    }
  }

  float sum = 0.0f;
  int myidx = 4095;
  float myval = 0.0f;
  #pragma unroll
  for (int e = 0; e < 32; ++e) {
    unsigned v = l0;
    #pragma unroll
    for (int o = 32; o > 0; o >>= 1) {
      unsigned w = (unsigned)__shfl_xor((int)v, o, 64);
      v = max(v, w);
    }
    if (l0 == v) {  // exactly one lane: keys globally unique
      l0 = l1; l1 = l2; l2 = l3; l3 = l4; l4 = l5; l5 = l6; l6 = l7; l7 = 0;
    }
    float val = h2f_bits(v >> 16);
    sum += val;
    if (lane == e) { myidx = 4095 - (int)(v & 0xFFFu); myval = val; }
  }
  int grow = b * NN + (q0 + rloc);
  if (lane < 32) {
    nidx[(size_t)grow * 32 + lane] = myidx;
    nval[(size_t)grow * 32 + lane] = myval;
  }
  if (lane == 0) {
    float tau = fmaxf(expf(p_log_tau[0]), 1e-3f);
    float deg = 0.9f * ((sum + 1.0f) / tau) + 0.1f;
    deg = fmaxf(deg, 1e-6f);
    dm12[grow] = 1.0f / sqrtf(deg);
  }
}

// ---- k_cheb1: T1 = Ahat @ h ---------------------------------------------------
__global__ __launch_bounds__(128) void k_cheb1(
    const float* __restrict__ h, const int* __restrict__ nidx,
    const float* __restrict__ nval, const float* __restrict__ dm12,
    const float* __restrict__ p_log_tau, float* __restrict__ T1) {
  int row = blockIdx.x;
  int b = row >> 12;
  int tid = threadIdx.x;
  __shared__ float cj[32];
  __shared__ int mj[32];
  __shared__ float cdsh;
  float tau = fmaxf(expf(p_log_tau[0]), 1e-3f);
  float scale = 0.9f / tau;
  float dn = dm12[row];
  if (tid < 32) {
    int m = nidx[(size_t)row * 32 + tid];
    cj[tid] = scale * nval[(size_t)row * 32 + tid] * dn * dm12[b * NN + m];
    mj[tid] = m;
  }
  if (tid == 0) cdsh = (scale + 0.1f) * dn * dn;
  __syncthreads();
  const float* hb = h + (size_t)b * NN * 128;
  float acc = cdsh * h[(size_t)row * 128 + tid];
  #pragma unroll 8
  for (int j = 0; j < 32; ++j)
    acc += cj[j] * hb[(size_t)mj[j] * 128 + tid];
  T1[(size_t)row * 128 + tid] = acc;
}

// ---- k_cheb2: T2 = 2*Ahat@T1 - T0 --------------------------------------------
__global__ __launch_bounds__(128) void k_cheb2(
    const float* __restrict__ h, const float* __restrict__ T1,
    const int* __restrict__ nidx, const float* __restrict__ nval,
    const float* __restrict__ dm12, const float* __restrict__ p_log_tau,
    float* __restrict__ T2) {
  int row = blockIdx.x;
  int b = row >> 12;
  int tid = threadIdx.x;
  __shared__ float cj[32];
  __shared__ int mj[32];
  __shared__ float cdsh;
  float tau = fmaxf(expf(p_log_tau[0]), 1e-3f);
  float scale = 0.9f / tau;
  float dn = dm12[row];
  if (tid < 32) {
    int m = nidx[(size_t)row * 32 + tid];
    cj[tid] = scale * nval[(size_t)row * 32 + tid] * dn * dm12[b * NN + m];
    mj[tid] = m;
  }
  if (tid == 0) cdsh = (scale + 0.1f) * dn * dn;
  __syncthreads();
  const float* T1b = T1 + (size_t)b * NN * 128;
  float a = cdsh * T1[(size_t)row * 128 + tid];
  #pragma unroll 8
  for (int j = 0; j < 32; ++j)
    a += cj[j] * T1b[(size_t)mj[j] * 128 + tid];
  T2[(size_t)row * 128 + tid] = 2.0f * a - h[(size_t)row * 128 + tid];
}

// ---- k_out: out = x + tanh(gate) * ([h|T1|T2] @ w2 + b2) ---------------------
__global__ __launch_bounds__(256) void k_out(
    const float* __restrict__ x, const float* __restrict__ h,
    const float* __restrict__ T1, const float* __restrict__ T2,
    const float* __restrict__ w2, const float* __restrict__ b2,
    const float* __restrict__ p_gate, float* __restrict__ out) {
  __shared__ float As[64][68];
  __shared__ float Bs[64][132];
  int tid = threadIdx.x;
  int tx = tid & 15, ty = tid >> 4;
  int rbase = blockIdx.x * 64;
  float acc[4][8];
  #pragma unroll
  for (int i = 0; i < 4; ++i)
    #pragma unroll
    for (int j = 0; j < 8; ++j) acc[i][j] = 0.0f;

  for (int kc = 0; kc < 6; ++kc) {
    const float* src = kc < 2 ? h : (kc < 4 ? T1 : T2);
    int ko = (kc & 1) * 64;
    #pragma unroll
    for (int i = 0; i < 4; ++i) {
      int idx = tid + 256 * i;
      int r = idx >> 4, c = idx & 15;
      *(float4*)&As[r][c * 4] = *(const float4*)(src + (size_t)(rbase + r) * 128 + ko + c * 4);
    }
    #pragma unroll
    for (int i = 0; i < 8; ++i) {
      int idx = tid + 256 * i;
      int r = idx >> 5, c = idx & 31;
      *(float4*)&Bs[r][c * 4] = *(const float4*)(w2 + (size_t)(kc * 64 + r) * 128 + c * 4);
    }
    __syncthreads();
    #pragma unroll 2
    for (int k = 0; k < 64; ++k) {
      float av[4], bv[8];
      #pragma unroll
      for (int i = 0; i < 4; ++i) av[i] = As[ty + 16 * i][k];
      #pragma unroll
      for (int j = 0; j < 8; ++j) bv[j] = Bs[k][tx + 16 * j];
      #pragma unroll
      for (int i = 0; i < 4; ++i)
        #pragma unroll
        for (int j = 0; j < 8; ++j) acc[i][j] += av[i] * bv[j];
    }
    __syncthreads();
  }
  float tg = tanhf(p_gate[0]);
  #pragma unroll
  for (int i = 0; i < 4; ++i) {
    int row = rbase + ty + 16 * i;
    #pragma unroll
    for (int j = 0; j < 8; ++j) {
      int col = tx + 16 * j;
      out[(size_t)row * 128 + col] =
          x[(size_t)row * 128 + col] + tg * (acc[i][j] + b2[col]);
    }
  }
}

extern "C" void kernel_launch(void* const* d_in, const int* in_sizes, int n_in,
                              void* d_out, int out_size, void* d_ws, size_t ws_size,
                              hipStream_t stream) {
  (void)in_sizes; (void)n_in; (void)out_size;
  const float* x = (const float*)d_in[0];
  const float* ln_g = (const float*)d_in[1];
  const float* ln_b = (const float*)d_in[2];
  const float* w1 = (const float*)d_in[3];
  const float* b1 = (const float*)d_in[4];
  const float* w2 = (const float*)d_in[5];
  const float* b2 = (const float*)d_in[6];
  const float* p_log_tau = (const float*)d_in[7];
  const float* p_gate = (const float*)d_in[8];
  float* out = (float*)d_out;

  char* ws = (char*)d_ws;
  size_t off = 0;
  auto alloc = [&](size_t bytes) -> void* {
    off = (off + 255) & ~(size_t)255;
    void* p = ws + off;
    off += bytes;
    return p;
  };
  float* h = (float*)alloc((size_t)NB * NN * 128 * 4);
  _Float16* hn16 = (_Float16*)alloc((size_t)NB * NN * 128 * 2);
  _Float16* ln16 = (_Float16*)alloc((size_t)NB * NN * 128 * 2);
  _Float16* w1t16 = (_Float16*)alloc((size_t)128 * 128 * 2);
  float* T1 = (float*)alloc((size_t)NB * NN * 128 * 4);
  float* T2 = (float*)alloc((size_t)NB * NN * 128 * 4);
  int* nidx = (int*)alloc((size_t)NB * NN * 32 * 4);
  float* nval = (float*)alloc((size_t)NB * NN * 32 * 4);
  float* dm12 = (float*)alloc((size_t)NB * NN * 4);
  off = (off + 255) & ~(size_t)255;
  size_t avail = (ws_size > off) ? (ws_size - off) : 0;
  long long Rll = (long long)(avail / ((size_t)NN * 2));
  int R = (int)((Rll > NN) ? NN : Rll);
  R = (R / 128) * 128;
  if (R > NN) R = NN;
  if (R < 128) R = 128;  // minimum viable chunk
  unsigned short* S = (unsigned short*)(ws + off);

  k_prep<<<128, 128, 0, stream>>>(w1, w1t16);
  k0_ln<<<NB * NN / 8, 128, 0, stream>>>(x, ln_g, ln_b, ln16);
  k1_mfma<<<NB * NN / 64, 256, 0, stream>>>(ln16, w1t16, b1, h);
  k_pack<<<NB * NN / 2, 256, 0, stream>>>(h, hn16);

  for (int b = 0; b < NB; ++b) {
    for (int q0 = 0; q0 < NN; q0 += R) {
      int rc = (NN - q0 < R) ? (NN - q0) : R;
      dim3 g(NN / 128, rc / 128);
      k_scores<<<g, 256, 0, stream>>>(hn16, S, b, q0);
      k_topk<<<(rc + 3) / 4, 256, 0, stream>>>(S, nidx, nval, dm12, p_log_tau, b, q0, rc);
    }
  }

  k_cheb1<<<NB * NN, 128, 0, stream>>>(h, nidx, nval, dm12, p_log_tau, T1);
  k_cheb2<<<NB * NN, 128, 0, stream>>>(h, T1, nidx, nval, dm12, p_log_tau, T2);
  k_out<<<NB * NN / 64, 256, 0, stream>>>(x, h, T1, T2, w2, b2, p_gate, out);
}

// Round 4
// 217.239 us; speedup vs baseline: 3.5028x; 1.1732x over previous
//
#include <hip/hip_runtime.h>
#include <hip/hip_bf16.h>
#include <stdint.h>

#define NB 4
#define NN 4096

using f16x8 = __attribute__((ext_vector_type(8))) _Float16;
using f32x4 = __attribute__((ext_vector_type(4))) float;

__device__ __forceinline__ float wave_sum(float v) {
  #pragma unroll
  for (int o = 32; o > 0; o >>= 1) v += __shfl_xor(v, o, 64);
  return v;
}
__device__ __forceinline__ float h2f_bits(unsigned hb) {
  unsigned short us = (unsigned short)hb;
  _Float16 hf;
  __builtin_memcpy(&hf, &us, 2);
  return (float)hf;
}
__device__ __forceinline__ unsigned short f2h_bits(float f) {
  _Float16 hf = (_Float16)f;
  unsigned short us;
  __builtin_memcpy(&us, &hf, 2);
  return us;
}
__device__ __forceinline__ unsigned pack2h(float lo, float hi) {
  return ((unsigned)f2h_bits(hi) << 16) | (unsigned)f2h_bits(lo);
}

// ---- k_prep: w1t16[n][k] = fp16(w1[k][n]), 16B chunks pre-swizzled c^=n&7 ----
__global__ __launch_bounds__(128) void k_prep(const float* __restrict__ w1,
                                              _Float16* __restrict__ w1t16) {
  int n = blockIdx.x;
  int k = threadIdx.x;
  __shared__ _Float16 v16[128];
  v16[k] = (_Float16)w1[(size_t)k * 128 + n];
  __syncthreads();
  if (k < 16) {
    union { _Float16 hh[8]; uint4 u; } pk;
    #pragma unroll
    for (int j = 0; j < 8; ++j) pk.hh[j] = v16[k * 8 + j];
    *(uint4*)(w1t16 + (size_t)n * 128 + (size_t)(k ^ (n & 7)) * 8) = pk.u;
  }
}

// ---- k_prep2: w2t16[n][k] = fp16(w2[k][n]), k in 0..383, chunks swizzled -----
__global__ __launch_bounds__(128) void k_prep2(const float* __restrict__ w2,
                                               _Float16* __restrict__ w2t16) {
  int n = blockIdx.x;
  int t = threadIdx.x;
  __shared__ float v[384];
  #pragma unroll
  for (int i = 0; i < 3; ++i) v[i * 128 + t] = w2[(size_t)(i * 128 + t) * 128 + n];
  __syncthreads();
  if (t < 48) {
    int kc = t >> 4, cl = t & 15;
    union { _Float16 hh[8]; uint4 u; } pk;
    #pragma unroll
    for (int e = 0; e < 8; ++e) pk.hh[e] = (_Float16)v[t * 8 + e];
    *(uint4*)(w2t16 + (size_t)n * 384 + kc * 128 + (size_t)(cl ^ (n & 7)) * 8) = pk.u;
  }
}

// ---- k0_ln: wave-per-row LayerNorm -> ln16 (fp16, swizzled), no barriers -----
__global__ __launch_bounds__(256) void k0_ln(
    const float* __restrict__ x, const float* __restrict__ ln_g,
    const float* __restrict__ ln_b, _Float16* __restrict__ ln16) {
  int lane = threadIdx.x & 63;
  int row = blockIdx.x * 4 + (threadIdx.x >> 6);
  float2 xv = ((const float2*)x)[(size_t)row * 64 + lane];
  float2 gv = ((const float2*)ln_g)[lane];
  float2 bv = ((const float2*)ln_b)[lane];
  float mu = wave_sum(xv.x + xv.y) * (1.0f / 128.0f);
  float dx = xv.x - mu, dy = xv.y - mu;
  float var = wave_sum(dx * dx + dy * dy) * (1.0f / 128.0f);
  float ri = 1.0f / sqrtf(var + 1e-5f);
  float h0 = dx * ri * gv.x + bv.x;
  float h1 = dy * ri * gv.y + bv.y;
  int c = lane >> 2;
  int addr = row * 128 + ((c ^ (row & 7)) << 3) + (lane & 3) * 2;
  *(unsigned*)(ln16 + addr) = pack2h(h0, h1);
}

// ---- k1_mfma: h = GELU(ln @ w1 + b1); writes h16 + hn16 (normalized), both
//      fp16 swizzled. Row norms computed in-register (16-lane shfl reduce). ----
__global__ __launch_bounds__(256) void k1_mfma(
    const _Float16* __restrict__ ln16, const _Float16* __restrict__ w1t16,
    const float* __restrict__ b1, _Float16* __restrict__ h16,
    _Float16* __restrict__ hn16) {
  __shared__ _Float16 As[64 * 128];
  __shared__ _Float16 Bs[128 * 128];
  int tid = threadIdx.x;
  int lane = tid & 63;
  int wv = tid >> 6;
  int rbase = blockIdx.x * 64;
  #pragma unroll
  for (int i = 0; i < 4; ++i) {
    int idx = tid + 256 * i;
    __builtin_amdgcn_global_load_lds(
        (const __attribute__((address_space(1))) void*)(ln16 + (size_t)rbase * 128 + (size_t)idx * 8),
        (__attribute__((address_space(3))) void*)(As + (size_t)idx * 8), 16, 0, 0);
  }
  #pragma unroll
  for (int i = 0; i < 8; ++i) {
    int idx = tid + 256 * i;
    __builtin_amdgcn_global_load_lds(
        (const __attribute__((address_space(1))) void*)(w1t16 + (size_t)idx * 8),
        (__attribute__((address_space(3))) void*)(Bs + (size_t)idx * 8), 16, 0, 0);
  }
  asm volatile("s_waitcnt vmcnt(0)" ::: "memory");
  __syncthreads();

  int rl = lane & 15, kg = lane >> 4;
  f32x4 acc[8];
  #pragma unroll
  for (int j = 0; j < 8; ++j) acc[j] = (f32x4){0.f, 0.f, 0.f, 0.f};
  #pragma unroll
  for (int kk = 0; kk < 4; ++kk) {
    int cL = kk * 4 + kg;
    int r = wv * 16 + rl;
    f16x8 a = *(const f16x8*)(As + r * 128 + (cL ^ (r & 7)) * 8);
    #pragma unroll
    for (int j = 0; j < 8; ++j) {
      int n = j * 16 + rl;
      f16x8 bf = *(const f16x8*)(Bs + n * 128 + (cL ^ (n & 7)) * 8);
      acc[j] = __builtin_amdgcn_mfma_f32_16x16x32_f16(a, bf, acc[j], 0, 0, 0);
    }
  }
  // bias + exact GELU; accumulate row sum of squares
  float ssq[4] = {0.f, 0.f, 0.f, 0.f};
  #pragma unroll
  for (int j = 0; j < 8; ++j) {
    float bv = b1[j * 16 + rl];
    #pragma unroll
    for (int rg = 0; rg < 4; ++rg) {
      float z = acc[j][rg] + bv;
      float g = 0.5f * z * (1.0f + erff(z * 0.70710678118654752440f));
      acc[j][rg] = g;
      ssq[rg] += g * g;
    }
  }
  #pragma unroll
  for (int o = 1; o < 16; o <<= 1)
    #pragma unroll
    for (int rg = 0; rg < 4; ++rg) ssq[rg] += __shfl_xor(ssq[rg], o, 64);
  float rinv[4];
  #pragma unroll
  for (int rg = 0; rg < 4; ++rg) rinv[rg] = 1.0f / fmaxf(sqrtf(ssq[rg]), 1e-12f);

  #pragma unroll
  for (int j = 0; j < 8; ++j) {
    #pragma unroll
    for (int rg = 0; rg < 4; ++rg) {
      float g = acc[j][rg];
      float gp = __shfl_xor(g, 1, 64);
      if ((rl & 1) == 0) {
        int row = rbase + wv * 16 + kg * 4 + rg;
        int col = j * 16 + rl;
        int c = col >> 3;
        int ad = row * 128 + (((c ^ (row & 7))) << 3) + (col & 7);
        *(unsigned*)(h16 + ad) = pack2h(g, gp);
        *(unsigned*)(hn16 + ad) = pack2h(g * rinv[rg], gp * rinv[rg]);
      }
    }
  }
}

// ---- k_scores: fp16 MFMA 128x128 tile, relu, fp16 store ----------------------
__global__ __launch_bounds__(256) void k_scores(
    const _Float16* __restrict__ hn16, unsigned short* __restrict__ S, int b, int q0) {
  __shared__ _Float16 Qs[128 * 128];
  __shared__ _Float16 Cs[128 * 128];
  int tid = threadIdx.x;
  int lane = tid & 63;
  int wv = tid >> 6;
  int wr = wv >> 1, wc = wv & 1;
  int cbase = blockIdx.x * 128;
  int qbase = q0 + blockIdx.y * 128;
  const _Float16* hq = hn16 + (size_t)b * NN * 128 + (size_t)qbase * 128;
  const _Float16* hc = hn16 + (size_t)b * NN * 128 + (size_t)cbase * 128;
  #pragma unroll
  for (int i = 0; i < 8; ++i) {
    int idx = tid + 256 * i;
    __builtin_amdgcn_global_load_lds(
        (const __attribute__((address_space(1))) void*)(hq + (size_t)idx * 8),
        (__attribute__((address_space(3))) void*)(Qs + (size_t)idx * 8), 16, 0, 0);
    __builtin_amdgcn_global_load_lds(
        (const __attribute__((address_space(1))) void*)(hc + (size_t)idx * 8),
        (__attribute__((address_space(3))) void*)(Cs + (size_t)idx * 8), 16, 0, 0);
  }
  asm volatile("s_waitcnt vmcnt(0)" ::: "memory");
  __syncthreads();

  f32x4 acc[4][4];
  #pragma unroll
  for (int i = 0; i < 4; ++i)
    #pragma unroll
    for (int j = 0; j < 4; ++j) acc[i][j] = (f32x4){0.f, 0.f, 0.f, 0.f};

  int rl = lane & 15;
  int kg = lane >> 4;
  #pragma unroll
  for (int kk = 0; kk < 4; ++kk) {
    int cL = kk * 4 + kg;
    f16x8 a[4], bb[4];
    #pragma unroll
    for (int i = 0; i < 4; ++i) {
      int r = wr * 64 + i * 16 + rl;
      a[i] = *(const f16x8*)(Qs + r * 128 + (cL ^ (r & 7)) * 8);
    }
    #pragma unroll
    for (int j = 0; j < 4; ++j) {
      int r = wc * 64 + j * 16 + rl;
      bb[j] = *(const f16x8*)(Cs + r * 128 + (cL ^ (r & 7)) * 8);
    }
    #pragma unroll
    for (int i = 0; i < 4; ++i)
      #pragma unroll
      for (int j = 0; j < 4; ++j)
        acc[i][j] = __builtin_amdgcn_mfma_f32_16x16x32_f16(a[i], bb[j], acc[i][j], 0, 0, 0);
  }
  int qloc0 = blockIdx.y * 128;
  #pragma unroll
  for (int i = 0; i < 4; ++i)
    #pragma unroll
    for (int j = 0; j < 4; ++j) {
      int q = qloc0 + wr * 64 + i * 16 + kg * 4;
      int m = cbase + wc * 64 + j * 16 + rl;
      #pragma unroll
      for (int rg = 0; rg < 4; ++rg)
        S[(size_t)(q + rg) * NN + m] = f2h_bits(fmaxf(acc[i][j][rg], 0.0f));
    }
}

// ---- k_topk: 1 wave/row, fp16 S, u32 keys, prefetched, branchless ------------
__global__ __launch_bounds__(256) void k_topk(
    const unsigned short* __restrict__ S, int* __restrict__ nidx,
    float* __restrict__ nval, float* __restrict__ dm12,
    const float* __restrict__ p_log_tau, int b, int q0, int nrows) {
  int wave = threadIdx.x >> 6;
  int lane = threadIdx.x & 63;
  int rloc = blockIdx.x * 4 + wave;
  if (rloc >= nrows) return;
  const unsigned short* Sr = S + (size_t)rloc * NN;
  uint4 ld[8];
  #pragma unroll
  for (int j = 0; j < 8; ++j)
    ld[j] = *(const uint4*)(Sr + j * 512 + lane * 8);

  unsigned l0 = 0, l1 = 0, l2 = 0, l3 = 0, l4 = 0, l5 = 0, l6 = 0, l7 = 0;
  #pragma unroll
  for (int j = 0; j < 8; ++j) {
    unsigned u[4] = {ld[j].x, ld[j].y, ld[j].z, ld[j].w};
    int cbase = j * 512 + lane * 8;
    #pragma unroll
    for (int t = 0; t < 4; ++t) {
      unsigned keyA = (u[t] << 16) | (unsigned)(4095 - (cbase + 2 * t));
      unsigned keyB = (u[t] & 0xFFFF0000u) | (unsigned)(4095 - (cbase + 2 * t + 1));
      unsigned c, tm;
      c = keyA;
      tm = max(l0, c); c = min(l0, c); l0 = tm;
      tm = max(l1, c); c = min(l1, c); l1 = tm;
      tm = max(l2, c); c = min(l2, c); l2 = tm;
      tm = max(l3, c); c = min(l3, c); l3 = tm;
      tm = max(l4, c); c = min(l4, c); l4 = tm;
      tm = max(l5, c); c = min(l5, c); l5 = tm;
      tm = max(l6, c); c = min(l6, c); l6 = tm;
      l7 = max(l7, c);
      c = keyB;
      tm = max(l0, c); c = min(l0, c); l0 = tm;
      tm = max(l1, c); c = min(l1, c); l1 = tm;
      tm = max(l2, c); c = min(l2, c); l2 = tm;
      tm = max(l3, c); c = min(l3, c); l3 = tm;
      tm = max(l4, c); c = min(l4, c); l4 = tm;
      tm = max(l5, c); c = min(l5, c); l5 = tm;
      tm = max(l6, c); c = min(l6, c); l6 = tm;
      l7 = max(l7, c);
    }
  }

  float sum = 0.0f;
  int myidx = 4095;
  float myval = 0.0f;
  #pragma unroll
  for (int e = 0; e < 32; ++e) {
    unsigned v = l0;
    #pragma unroll
    for (int o = 32; o > 0; o >>= 1) {
      unsigned w = (unsigned)__shfl_xor((int)v, o, 64);
      v = max(v, w);
    }
    if (l0 == v) {
      l0 = l1; l1 = l2; l2 = l3; l3 = l4; l4 = l5; l5 = l6; l6 = l7; l7 = 0;
    }
    float val = h2f_bits(v >> 16);
    sum += val;
    if (lane == e) { myidx = 4095 - (int)(v & 0xFFFu); myval = val; }
  }
  int grow = b * NN + (q0 + rloc);
  if (lane < 32) {
    nidx[(size_t)grow * 32 + lane] = myidx;
    nval[(size_t)grow * 32 + lane] = myval;
  }
  if (lane == 0) {
    float tau = fmaxf(expf(p_log_tau[0]), 1e-3f);
    float deg = 0.9f * ((sum + 1.0f) / tau) + 0.1f;
    deg = fmaxf(deg, 1e-6f);
    dm12[grow] = 1.0f / sqrtf(deg);
  }
}

// ---- k_cheb1: T1 = Ahat @ h (fp16 gather in, fp16 swizzled out) --------------
__global__ __launch_bounds__(128) void k_cheb1(
    const _Float16* __restrict__ h16, const int* __restrict__ nidx,
    const float* __restrict__ nval, const float* __restrict__ dm12,
    const float* __restrict__ p_log_tau, _Float16* __restrict__ T116) {
  int row = blockIdx.x;
  int b = row >> 12;
  int tid = threadIdx.x;
  __shared__ float cj[32];
  __shared__ int mj[32];
  __shared__ float cdsh;
  float tau = fmaxf(expf(p_log_tau[0]), 1e-3f);
  float scale = 0.9f / tau;
  float dn = dm12[row];
  if (tid < 32) {
    int m = nidx[(size_t)row * 32 + tid];
    cj[tid] = scale * nval[(size_t)row * 32 + tid] * dn * dm12[b * NN + m];
    mj[tid] = m;
  }
  if (tid == 0) cdsh = (scale + 0.1f) * dn * dn;
  __syncthreads();
  int c = tid >> 3, e = tid & 7;
  const _Float16* hb = h16 + (size_t)b * NN * 128;
  float acc = cdsh * (float)h16[(size_t)row * 128 + ((c ^ (row & 7)) << 3) + e];
  #pragma unroll 8
  for (int j = 0; j < 32; ++j) {
    int m = mj[j];
    acc += cj[j] * (float)hb[(size_t)m * 128 + ((c ^ (m & 7)) << 3) + e];
  }
  float p = __shfl_xor(acc, 1, 64);
  if (!(tid & 1))
    *(unsigned*)(T116 + (size_t)row * 128 + ((c ^ (row & 7)) << 3) + e) = pack2h(acc, p);
}

// ---- k_cheb2: T2 = 2*Ahat@T1 - h (fp16 in/out) -------------------------------
__global__ __launch_bounds__(128) void k_cheb2(
    const _Float16* __restrict__ h16, const _Float16* __restrict__ T116,
    const int* __restrict__ nidx, const float* __restrict__ nval,
    const float* __restrict__ dm12, const float* __restrict__ p_log_tau,
    _Float16* __restrict__ T216) {
  int row = blockIdx.x;
  int b = row >> 12;
  int tid = threadIdx.x;
  __shared__ float cj[32];
  __shared__ int mj[32];
  __shared__ float cdsh;
  float tau = fmaxf(expf(p_log_tau[0]), 1e-3f);
  float scale = 0.9f / tau;
  float dn = dm12[row];
  if (tid < 32) {
    int m = nidx[(size_t)row * 32 + tid];
    cj[tid] = scale * nval[(size_t)row * 32 + tid] * dn * dm12[b * NN + m];
    mj[tid] = m;
  }
  if (tid == 0) cdsh = (scale + 0.1f) * dn * dn;
  __syncthreads();
  int c = tid >> 3, e = tid & 7;
  int sw_own = ((c ^ (row & 7)) << 3) + e;
  const _Float16* T1b = T116 + (size_t)b * NN * 128;
  float a = cdsh * (float)T116[(size_t)row * 128 + sw_own];
  #pragma unroll 8
  for (int j = 0; j < 32; ++j) {
    int m = mj[j];
    a += cj[j] * (float)T1b[(size_t)m * 128 + ((c ^ (m & 7)) << 3) + e];
  }
  float t2 = 2.0f * a - (float)h16[(size_t)row * 128 + sw_own];
  float p = __shfl_xor(t2, 1, 64);
  if (!(tid & 1))
    *(unsigned*)(T216 + (size_t)row * 128 + sw_own) = pack2h(t2, p);
}

// ---- k_out: out = x + tanh(gate)*([h|T1|T2] @ w2 + b2); fp16 MFMA, one-shot
//      LDS stage of all K-chunks (144 KB), single barrier. --------------------
__global__ __launch_bounds__(256, 1) void k_out(
    const float* __restrict__ x, const _Float16* __restrict__ h16,
    const _Float16* __restrict__ T116, const _Float16* __restrict__ T216,
    const _Float16* __restrict__ w2t16, const float* __restrict__ b2,
    const float* __restrict__ p_gate, float* __restrict__ out) {
  __shared__ _Float16 As3[3][64 * 128];    // 48 KB
  __shared__ _Float16 Bs3[3][128 * 128];   // 96 KB
  int tid = threadIdx.x;
  int lane = tid & 63;
  int wv = tid >> 6;
  int rbase = blockIdx.x * 64;
  const _Float16* srcs[3] = {h16, T116, T216};
  #pragma unroll
  for (int kc = 0; kc < 3; ++kc) {
    const _Float16* src = srcs[kc] + (size_t)rbase * 128;
    #pragma unroll
    for (int i = 0; i < 4; ++i) {
      int idx = tid + 256 * i;
      __builtin_amdgcn_global_load_lds(
          (const __attribute__((address_space(1))) void*)(src + (size_t)idx * 8),
          (__attribute__((address_space(3))) void*)(As3[kc] + (size_t)idx * 8), 16, 0, 0);
    }
    #pragma unroll
    for (int i = 0; i < 8; ++i) {
      int idx = tid + 256 * i;
      int n = idx >> 4, cp = idx & 15;
      __builtin_amdgcn_global_load_lds(
          (const __attribute__((address_space(1))) void*)(w2t16 + (size_t)n * 384 + kc * 128 + (size_t)cp * 8),
          (__attribute__((address_space(3))) void*)(Bs3[kc] + (size_t)idx * 8), 16, 0, 0);
    }
  }
  asm volatile("s_waitcnt vmcnt(0)" ::: "memory");
  __syncthreads();

  int rl = lane & 15, kg = lane >> 4;
  f32x4 acc[8];
  #pragma unroll
  for (int j = 0; j < 8; ++j) acc[j] = (f32x4){0.f, 0.f, 0.f, 0.f};
  #pragma unroll
  for (int kc = 0; kc < 3; ++kc) {
    #pragma unroll
    for (int kk = 0; kk < 4; ++kk) {
      int cL = kk * 4 + kg;
      int r = wv * 16 + rl;
      f16x8 a = *(const f16x8*)(As3[kc] + r * 128 + (cL ^ (r & 7)) * 8);
      #pragma unroll
      for (int j = 0; j < 8; ++j) {
        int n = j * 16 + rl;
        f16x8 bf = *(const f16x8*)(Bs3[kc] + n * 128 + (cL ^ (n & 7)) * 8);
        acc[j] = __builtin_amdgcn_mfma_f32_16x16x32_f16(a, bf, acc[j], 0, 0, 0);
      }
    }
  }
  float tg = tanhf(p_gate[0]);
  #pragma unroll
  for (int j = 0; j < 8; ++j) {
    int col = j * 16 + rl;
    float bv = b2[col];
    #pragma unroll
    for (int rg = 0; rg < 4; ++rg) {
      int row = rbase + wv * 16 + kg * 4 + rg;
      out[(size_t)row * 128 + col] =
          x[(size_t)row * 128 + col] + tg * (acc[j][rg] + bv);
    }
  }
}

extern "C" void kernel_launch(void* const* d_in, const int* in_sizes, int n_in,
                              void* d_out, int out_size, void* d_ws, size_t ws_size,
                              hipStream_t stream) {
  (void)in_sizes; (void)n_in; (void)out_size;
  const float* x = (const float*)d_in[0];
  const float* ln_g = (const float*)d_in[1];
  const float* ln_b = (const float*)d_in[2];
  const float* w1 = (const float*)d_in[3];
  const float* b1 = (const float*)d_in[4];
  const float* w2 = (const float*)d_in[5];
  const float* b2 = (const float*)d_in[6];
  const float* p_log_tau = (const float*)d_in[7];
  const float* p_gate = (const float*)d_in[8];
  float* out = (float*)d_out;

  char* ws = (char*)d_ws;
  size_t off = 0;
  auto alloc = [&](size_t bytes) -> void* {
    off = (off + 255) & ~(size_t)255;
    void* p = ws + off;
    off += bytes;
    return p;
  };
  _Float16* ln16 = (_Float16*)alloc((size_t)NB * NN * 128 * 2);
  _Float16* h16 = (_Float16*)alloc((size_t)NB * NN * 128 * 2);
  _Float16* hn16 = (_Float16*)alloc((size_t)NB * NN * 128 * 2);
  _Float16* T116 = (_Float16*)alloc((size_t)NB * NN * 128 * 2);
  _Float16* T216 = (_Float16*)alloc((size_t)NB * NN * 128 * 2);
  _Float16* w1t16 = (_Float16*)alloc((size_t)128 * 128 * 2);
  _Float16* w2t16 = (_Float16*)alloc((size_t)128 * 384 * 2);
  int* nidx = (int*)alloc((size_t)NB * NN * 32 * 4);
  float* nval = (float*)alloc((size_t)NB * NN * 32 * 4);
  float* dm12 = (float*)alloc((size_t)NB * NN * 4);
  off = (off + 255) & ~(size_t)255;
  size_t avail = (ws_size > off) ? (ws_size - off) : 0;
  long long Rll = (long long)(avail / ((size_t)NN * 2));
  int R = (int)((Rll > NN) ? NN : Rll);
  R = (R / 128) * 128;
  if (R > NN) R = NN;
  if (R < 128) R = 128;  // minimum viable chunk
  unsigned short* S = (unsigned short*)(ws + off);

  k_prep<<<128, 128, 0, stream>>>(w1, w1t16);
  k_prep2<<<128, 128, 0, stream>>>(w2, w2t16);
  k0_ln<<<NB * NN / 4, 256, 0, stream>>>(x, ln_g, ln_b, ln16);
  k1_mfma<<<NB * NN / 64, 256, 0, stream>>>(ln16, w1t16, b1, h16, hn16);

  for (int b = 0; b < NB; ++b) {
    for (int q0 = 0; q0 < NN; q0 += R) {
      int rc = (NN - q0 < R) ? (NN - q0) : R;
      dim3 g(NN / 128, rc / 128);
      k_scores<<<g, 256, 0, stream>>>(hn16, S, b, q0);
      k_topk<<<(rc + 3) / 4, 256, 0, stream>>>(S, nidx, nval, dm12, p_log_tau, b, q0, rc);
    }
  }

  k_cheb1<<<NB * NN, 128, 0, stream>>>(h16, nidx, nval, dm12, p_log_tau, T116);
  k_cheb2<<<NB * NN, 128, 0, stream>>>(h16, T116, nidx, nval, dm12, p_log_tau, T216);
  k_out<<<NB * NN / 64, 256, 0, stream>>>(x, h16, T116, T216, w2t16, b2, p_gate, out);
}

// Round 5
// 191.369 us; speedup vs baseline: 3.9763x; 1.1352x over previous
//
#include <hip/hip_runtime.h>
#include <hip/hip_bf16.h>
#include <stdint.h>

#define NB 4
#define NN 4096

using f16x8 = __attribute__((ext_vector_type(8))) _Float16;
using f32x4 = __attribute__((ext_vector_type(4))) float;

__device__ __forceinline__ float wave_sum(float v) {
  #pragma unroll
  for (int o = 32; o > 0; o >>= 1) v += __shfl_xor(v, o, 64);
  return v;
}
__device__ __forceinline__ float h2f_bits(unsigned hb) {
  unsigned short us = (unsigned short)hb;
  _Float16 hf;
  __builtin_memcpy(&hf, &us, 2);
  return (float)hf;
}
__device__ __forceinline__ unsigned short f2h_bits(float f) {
  _Float16 hf = (_Float16)f;
  unsigned short us;
  __builtin_memcpy(&us, &hf, 2);
  return us;
}
__device__ __forceinline__ unsigned pack2h(float lo, float hi) {
  return ((unsigned)f2h_bits(hi) << 16) | (unsigned)f2h_bits(lo);
}

// 16-deep branchless sorted-insert cascade (desc). c is clobbered.
#define INS16(c) do { unsigned t_;                      \
  t_ = max(l0, c);  c = min(l0, c);  l0 = t_;           \
  t_ = max(l1, c);  c = min(l1, c);  l1 = t_;           \
  t_ = max(l2, c);  c = min(l2, c);  l2 = t_;           \
  t_ = max(l3, c);  c = min(l3, c);  l3 = t_;           \
  t_ = max(l4, c);  c = min(l4, c);  l4 = t_;           \
  t_ = max(l5, c);  c = min(l5, c);  l5 = t_;           \
  t_ = max(l6, c);  c = min(l6, c);  l6 = t_;           \
  t_ = max(l7, c);  c = min(l7, c);  l7 = t_;           \
  t_ = max(l8, c);  c = min(l8, c);  l8 = t_;           \
  t_ = max(l9, c);  c = min(l9, c);  l9 = t_;           \
  t_ = max(l10, c); c = min(l10, c); l10 = t_;          \
  t_ = max(l11, c); c = min(l11, c); l11 = t_;          \
  t_ = max(l12, c); c = min(l12, c); l12 = t_;          \
  t_ = max(l13, c); c = min(l13, c); l13 = t_;          \
  t_ = max(l14, c); c = min(l14, c); l14 = t_;          \
  l15 = max(l15, c);                                    \
} while (0)

// ---- k_prep: w1t16[n][k] = fp16(w1[k][n]), 16B chunks pre-swizzled c^=n&7 ----
__global__ __launch_bounds__(128) void k_prep(const float* __restrict__ w1,
                                              _Float16* __restrict__ w1t16) {
  int n = blockIdx.x;
  int k = threadIdx.x;
  __shared__ _Float16 v16[128];
  v16[k] = (_Float16)w1[(size_t)k * 128 + n];
  __syncthreads();
  if (k < 16) {
    union { _Float16 hh[8]; uint4 u; } pk;
    #pragma unroll
    for (int j = 0; j < 8; ++j) pk.hh[j] = v16[k * 8 + j];
    *(uint4*)(w1t16 + (size_t)n * 128 + (size_t)(k ^ (n & 7)) * 8) = pk.u;
  }
}

// ---- k_prep2: w2t16[n][k] = fp16(w2[k][n]), k in 0..383, chunks swizzled -----
__global__ __launch_bounds__(128) void k_prep2(const float* __restrict__ w2,
                                               _Float16* __restrict__ w2t16) {
  int n = blockIdx.x;
  int t = threadIdx.x;
  __shared__ float v[384];
  #pragma unroll
  for (int i = 0; i < 3; ++i) v[i * 128 + t] = w2[(size_t)(i * 128 + t) * 128 + n];
  __syncthreads();
  if (t < 48) {
    int kc = t >> 4, cl = t & 15;
    union { _Float16 hh[8]; uint4 u; } pk;
    #pragma unroll
    for (int e = 0; e < 8; ++e) pk.hh[e] = (_Float16)v[t * 8 + e];
    *(uint4*)(w2t16 + (size_t)n * 384 + kc * 128 + (size_t)(cl ^ (n & 7)) * 8) = pk.u;
  }
}

// ---- k0_ln: wave-per-row LayerNorm -> ln16 (fp16, swizzled), no barriers -----
__global__ __launch_bounds__(256) void k0_ln(
    const float* __restrict__ x, const float* __restrict__ ln_g,
    const float* __restrict__ ln_b, _Float16* __restrict__ ln16) {
  int lane = threadIdx.x & 63;
  int row = blockIdx.x * 4 + (threadIdx.x >> 6);
  float2 xv = ((const float2*)x)[(size_t)row * 64 + lane];
  float2 gv = ((const float2*)ln_g)[lane];
  float2 bv = ((const float2*)ln_b)[lane];
  float mu = wave_sum(xv.x + xv.y) * (1.0f / 128.0f);
  float dx = xv.x - mu, dy = xv.y - mu;
  float var = wave_sum(dx * dx + dy * dy) * (1.0f / 128.0f);
  float ri = 1.0f / sqrtf(var + 1e-5f);
  float h0 = dx * ri * gv.x + bv.x;
  float h1 = dy * ri * gv.y + bv.y;
  int c = lane >> 2;
  int addr = row * 128 + ((c ^ (row & 7)) << 3) + (lane & 3) * 2;
  *(unsigned*)(ln16 + addr) = pack2h(h0, h1);
}

// ---- k1_mfma: h = GELU(ln @ w1 + b1); writes h16 + hn16 (normalized) ---------
__global__ __launch_bounds__(256) void k1_mfma(
    const _Float16* __restrict__ ln16, const _Float16* __restrict__ w1t16,
    const float* __restrict__ b1, _Float16* __restrict__ h16,
    _Float16* __restrict__ hn16) {
  __shared__ _Float16 As[64 * 128];
  __shared__ _Float16 Bs[128 * 128];
  int tid = threadIdx.x;
  int lane = tid & 63;
  int wv = tid >> 6;
  int rbase = blockIdx.x * 64;
  #pragma unroll
  for (int i = 0; i < 4; ++i) {
    int idx = tid + 256 * i;
    __builtin_amdgcn_global_load_lds(
        (const __attribute__((address_space(1))) void*)(ln16 + (size_t)rbase * 128 + (size_t)idx * 8),
        (__attribute__((address_space(3))) void*)(As + (size_t)idx * 8), 16, 0, 0);
  }
  #pragma unroll
  for (int i = 0; i < 8; ++i) {
    int idx = tid + 256 * i;
    __builtin_amdgcn_global_load_lds(
        (const __attribute__((address_space(1))) void*)(w1t16 + (size_t)idx * 8),
        (__attribute__((address_space(3))) void*)(Bs + (size_t)idx * 8), 16, 0, 0);
  }
  asm volatile("s_waitcnt vmcnt(0)" ::: "memory");
  __syncthreads();

  int rl = lane & 15, kg = lane >> 4;
  f32x4 acc[8];
  #pragma unroll
  for (int j = 0; j < 8; ++j) acc[j] = (f32x4){0.f, 0.f, 0.f, 0.f};
  #pragma unroll
  for (int kk = 0; kk < 4; ++kk) {
    int cL = kk * 4 + kg;
    int r = wv * 16 + rl;
    f16x8 a = *(const f16x8*)(As + r * 128 + (cL ^ (r & 7)) * 8);
    #pragma unroll
    for (int j = 0; j < 8; ++j) {
      int n = j * 16 + rl;
      f16x8 bf = *(const f16x8*)(Bs + n * 128 + (cL ^ (n & 7)) * 8);
      acc[j] = __builtin_amdgcn_mfma_f32_16x16x32_f16(a, bf, acc[j], 0, 0, 0);
    }
  }
  float ssq[4] = {0.f, 0.f, 0.f, 0.f};
  #pragma unroll
  for (int j = 0; j < 8; ++j) {
    float bv = b1[j * 16 + rl];
    #pragma unroll
    for (int rg = 0; rg < 4; ++rg) {
      float z = acc[j][rg] + bv;
      float g = 0.5f * z * (1.0f + erff(z * 0.70710678118654752440f));
      acc[j][rg] = g;
      ssq[rg] += g * g;
    }
  }
  #pragma unroll
  for (int o = 1; o < 16; o <<= 1)
    #pragma unroll
    for (int rg = 0; rg < 4; ++rg) ssq[rg] += __shfl_xor(ssq[rg], o, 64);
  float rinv[4];
  #pragma unroll
  for (int rg = 0; rg < 4; ++rg) rinv[rg] = 1.0f / fmaxf(sqrtf(ssq[rg]), 1e-12f);

  #pragma unroll
  for (int j = 0; j < 8; ++j) {
    #pragma unroll
    for (int rg = 0; rg < 4; ++rg) {
      float g = acc[j][rg];
      float gp = __shfl_xor(g, 1, 64);
      if ((rl & 1) == 0) {
        int row = rbase + wv * 16 + kg * 4 + rg;
        int col = j * 16 + rl;
        int c = col >> 3;
        int ad = row * 128 + (((c ^ (row & 7))) << 3) + (col & 7);
        *(unsigned*)(h16 + ad) = pack2h(g, gp);
        *(unsigned*)(hn16 + ad) = pack2h(g * rinv[rg], gp * rinv[rg]);
      }
    }
  }
}

// ---- k_scores_topk: FUSED. Per block: 64 queries, loop 32 col-blocks of 128.
//      mfma(C,Q) -> D[m][q]: query lives in lane (q = lane&15); 4 lanes/query
//      keep exact 16-deep lists over disjoint m-quarters via LDS stacks. ------
__global__ __launch_bounds__(256, 1) void k_scores_topk(
    const _Float16* __restrict__ hn16, int* __restrict__ nidx,
    float* __restrict__ nval, float* __restrict__ dm12,
    const float* __restrict__ p_log_tau) {
  __shared__ _Float16 Qs[64 * 128];       // 16 KB
  __shared__ _Float16 Cs[2][128 * 128];   // 64 KB (double-buffered)
  __shared__ unsigned stk[32 * 256];      // 32 KB per-lane candidate stacks
  int tid = threadIdx.x;
  int lane = tid & 63;
  int wv = tid >> 6;
  int rl = lane & 15, kg = lane >> 4;
  int blk = blockIdx.x;
  int b = blk >> 6;
  int qbase = (blk & 63) * 64;
  const _Float16* hb = hn16 + (size_t)b * NN * 128;

  #pragma unroll
  for (int i = 0; i < 4; ++i) {
    int idx = tid + 256 * i;
    __builtin_amdgcn_global_load_lds(
        (const __attribute__((address_space(1))) void*)(hb + (size_t)qbase * 128 + (size_t)idx * 8),
        (__attribute__((address_space(3))) void*)(Qs + (size_t)idx * 8), 16, 0, 0);
  }
  #pragma unroll
  for (int i = 0; i < 8; ++i) {
    int idx = tid + 256 * i;
    __builtin_amdgcn_global_load_lds(
        (const __attribute__((address_space(1))) void*)(hb + (size_t)idx * 8),
        (__attribute__((address_space(3))) void*)(Cs[0] + (size_t)idx * 8), 16, 0, 0);
  }
  asm volatile("s_waitcnt vmcnt(0)" ::: "memory");
  __syncthreads();

  // Q fragments fixed for whole kernel: B[k][col=q], lane supplies Q[q=qrow][k]
  int qrow = wv * 16 + rl;
  f16x8 bq[4];
  #pragma unroll
  for (int kk = 0; kk < 4; ++kk)
    bq[kk] = *(const f16x8*)(Qs + qrow * 128 + ((kk * 4 + kg) ^ (qrow & 7)) * 8);

  unsigned l0 = 0, l1 = 0, l2 = 0, l3 = 0, l4 = 0, l5 = 0, l6 = 0, l7 = 0,
           l8 = 0, l9 = 0, l10 = 0, l11 = 0, l12 = 0, l13 = 0, l14 = 0, l15 = 0;

  for (int cb = 0; cb < 32; ++cb) {
    int cur = cb & 1;
    if (cb < 31) {  // prefetch next C tile into other buffer
      const _Float16* csrc = hb + (size_t)(cb + 1) * 128 * 128;
      #pragma unroll
      for (int i = 0; i < 8; ++i) {
        int idx = tid + 256 * i;
        __builtin_amdgcn_global_load_lds(
            (const __attribute__((address_space(1))) void*)(csrc + (size_t)idx * 8),
            (__attribute__((address_space(3))) void*)(Cs[cur ^ 1] + (size_t)idx * 8), 16, 0, 0);
      }
    }
    f32x4 acc[8];
    #pragma unroll
    for (int j = 0; j < 8; ++j) acc[j] = (f32x4){0.f, 0.f, 0.f, 0.f};
    #pragma unroll
    for (int kk = 0; kk < 4; ++kk) {
      #pragma unroll
      for (int j = 0; j < 8; ++j) {
        int mrow = j * 16 + rl;
        f16x8 a = *(const f16x8*)(Cs[cur] + mrow * 128 + ((kk * 4 + kg) ^ (rl & 7)) * 8);
        acc[j] = __builtin_amdgcn_mfma_f32_16x16x32_f16(a, bq[kk], acc[j], 0, 0, 0);
      }
    }
    // scan 32 scores: m = cb*128 + j*16 + kg*4 + rg; gate into LDS stack
    int cnt = 0;
    int mbase = cb * 128 + kg * 4;
    #pragma unroll
    for (int j = 0; j < 8; ++j) {
      #pragma unroll
      for (int rg = 0; rg < 4; ++rg) {
        float v = fmaxf(acc[j][rg], 0.0f);
        int m = mbase + j * 16 + rg;
        unsigned key = ((unsigned)f2h_bits(v) << 16) | (unsigned)(4095 - m);
        if (key > l15) {
          stk[cnt * 256 + tid] = key;
          ++cnt;
        }
      }
    }
    // drain stacks (per-lane parallel, bounded by wave-max cnt <= 32)
    for (int i = 0;; ++i) {
      if (__ballot(i < cnt) == 0ull) break;
      unsigned c = (i < cnt) ? stk[i * 256 + tid] : 0u;
      INS16(c);
    }
    asm volatile("s_waitcnt vmcnt(0)" ::: "memory");
    __syncthreads();
  }

  // exact top-32 = 32 rounds of 4-lane (xor 16/32) max-merge with pop
  unsigned sv[8];
  float sum = 0.0f;
  #pragma unroll
  for (int e = 0; e < 32; ++e) {
    unsigned v = l0;
    v = max(v, (unsigned)__shfl_xor((int)v, 16, 64));
    v = max(v, (unsigned)__shfl_xor((int)v, 32, 64));
    if (l0 == v) {  // unique keys -> exactly one popper
      l0 = l1; l1 = l2; l2 = l3; l3 = l4; l4 = l5; l5 = l6; l6 = l7; l7 = l8;
      l8 = l9; l9 = l10; l10 = l11; l11 = l12; l12 = l13; l13 = l14; l14 = l15; l15 = 0;
    }
    sum += h2f_bits(v >> 16);
    if (kg == (e & 3)) sv[e >> 2] = v;
  }
  int grow = b * NN + qbase + qrow;
  #pragma unroll
  for (int s = 0; s < 8; ++s) {
    unsigned v = sv[s];
    nidx[(size_t)grow * 32 + s * 4 + kg] = 4095 - (int)(v & 0xFFFu);
    nval[(size_t)grow * 32 + s * 4 + kg] = h2f_bits(v >> 16);
  }
  if (kg == 0) {
    float tau = fmaxf(expf(p_log_tau[0]), 1e-3f);
    float deg = fmaxf(0.9f * ((sum + 1.0f) / tau) + 0.1f, 1e-6f);
    dm12[grow] = 1.0f / sqrtf(deg);
  }
}

// ---- k_cheb1: T1 = Ahat @ h (fp16 gather in, fp16 swizzled out) --------------
__global__ __launch_bounds__(128) void k_cheb1(
    const _Float16* __restrict__ h16, const int* __restrict__ nidx,
    const float* __restrict__ nval, const float* __restrict__ dm12,
    const float* __restrict__ p_log_tau, _Float16* __restrict__ T116) {
  int row = blockIdx.x;
  int b = row >> 12;
  int tid = threadIdx.x;
  __shared__ float cj[32];
  __shared__ int mj[32];
  __shared__ float cdsh;
  float tau = fmaxf(expf(p_log_tau[0]), 1e-3f);
  float scale = 0.9f / tau;
  float dn = dm12[row];
  if (tid < 32) {
    int m = nidx[(size_t)row * 32 + tid];
    cj[tid] = scale * nval[(size_t)row * 32 + tid] * dn * dm12[b * NN + m];
    mj[tid] = m;
  }
  if (tid == 0) cdsh = (scale + 0.1f) * dn * dn;
  __syncthreads();
  int c = tid >> 3, e = tid & 7;
  const _Float16* hb = h16 + (size_t)b * NN * 128;
  float acc = cdsh * (float)h16[(size_t)row * 128 + ((c ^ (row & 7)) << 3) + e];
  #pragma unroll 8
  for (int j = 0; j < 32; ++j) {
    int m = mj[j];
    acc += cj[j] * (float)hb[(size_t)m * 128 + ((c ^ (m & 7)) << 3) + e];
  }
  float p = __shfl_xor(acc, 1, 64);
  if (!(tid & 1))
    *(unsigned*)(T116 + (size_t)row * 128 + ((c ^ (row & 7)) << 3) + e) = pack2h(acc, p);
}

// ---- k_cheb2: T2 = 2*Ahat@T1 - h (fp16 in/out) -------------------------------
__global__ __launch_bounds__(128) void k_cheb2(
    const _Float16* __restrict__ h16, const _Float16* __restrict__ T116,
    const int* __restrict__ nidx, const float* __restrict__ nval,
    const float* __restrict__ dm12, const float* __restrict__ p_log_tau,
    _Float16* __restrict__ T216) {
  int row = blockIdx.x;
  int b = row >> 12;
  int tid = threadIdx.x;
  __shared__ float cj[32];
  __shared__ int mj[32];
  __shared__ float cdsh;
  float tau = fmaxf(expf(p_log_tau[0]), 1e-3f);
  float scale = 0.9f / tau;
  float dn = dm12[row];
  if (tid < 32) {
    int m = nidx[(size_t)row * 32 + tid];
    cj[tid] = scale * nval[(size_t)row * 32 + tid] * dn * dm12[b * NN + m];
    mj[tid] = m;
  }
  if (tid == 0) cdsh = (scale + 0.1f) * dn * dn;
  __syncthreads();
  int c = tid >> 3, e = tid & 7;
  int sw_own = ((c ^ (row & 7)) << 3) + e;
  const _Float16* T1b = T116 + (size_t)b * NN * 128;
  float a = cdsh * (float)T116[(size_t)row * 128 + sw_own];
  #pragma unroll 8
  for (int j = 0; j < 32; ++j) {
    int m = mj[j];
    a += cj[j] * (float)T1b[(size_t)m * 128 + ((c ^ (m & 7)) << 3) + e];
  }
  float t2 = 2.0f * a - (float)h16[(size_t)row * 128 + sw_own];
  float p = __shfl_xor(t2, 1, 64);
  if (!(tid & 1))
    *(unsigned*)(T216 + (size_t)row * 128 + sw_own) = pack2h(t2, p);
}

// ---- k_out: out = x + tanh(gate)*([h|T1|T2] @ w2 + b2); fp16 MFMA ------------
__global__ __launch_bounds__(256, 1) void k_out(
    const float* __restrict__ x, const _Float16* __restrict__ h16,
    const _Float16* __restrict__ T116, const _Float16* __restrict__ T216,
    const _Float16* __restrict__ w2t16, const float* __restrict__ b2,
    const float* __restrict__ p_gate, float* __restrict__ out) {
  __shared__ _Float16 As3[3][64 * 128];
  __shared__ _Float16 Bs3[3][128 * 128];
  int tid = threadIdx.x;
  int lane = tid & 63;
  int wv = tid >> 6;
  int rbase = blockIdx.x * 64;
  const _Float16* srcs[3] = {h16, T116, T216};
  #pragma unroll
  for (int kc = 0; kc < 3; ++kc) {
    const _Float16* src = srcs[kc] + (size_t)rbase * 128;
    #pragma unroll
    for (int i = 0; i < 4; ++i) {
      int idx = tid + 256 * i;
      __builtin_amdgcn_global_load_lds(
          (const __attribute__((address_space(1))) void*)(src + (size_t)idx * 8),
          (__attribute__((address_space(3))) void*)(As3[kc] + (size_t)idx * 8), 16, 0, 0);
    }
    #pragma unroll
    for (int i = 0; i < 8; ++i) {
      int idx = tid + 256 * i;
      int n = idx >> 4, cp = idx & 15;
      __builtin_amdgcn_global_load_lds(
          (const __attribute__((address_space(1))) void*)(w2t16 + (size_t)n * 384 + kc * 128 + (size_t)cp * 8),
          (__attribute__((address_space(3))) void*)(Bs3[kc] + (size_t)idx * 8), 16, 0, 0);
    }
  }
  asm volatile("s_waitcnt vmcnt(0)" ::: "memory");
  __syncthreads();

  int rl = lane & 15, kg = lane >> 4;
  f32x4 acc[8];
  #pragma unroll
  for (int j = 0; j < 8; ++j) acc[j] = (f32x4){0.f, 0.f, 0.f, 0.f};
  #pragma unroll
  for (int kc = 0; kc < 3; ++kc) {
    #pragma unroll
    for (int kk = 0; kk < 4; ++kk) {
      int cL = kk * 4 + kg;
      int r = wv * 16 + rl;
      f16x8 a = *(const f16x8*)(As3[kc] + r * 128 + (cL ^ (r & 7)) * 8);
      #pragma unroll
      for (int j = 0; j < 8; ++j) {
        int n = j * 16 + rl;
        f16x8 bf = *(const f16x8*)(Bs3[kc] + n * 128 + (cL ^ (n & 7)) * 8);
        acc[j] = __builtin_amdgcn_mfma_f32_16x16x32_f16(a, bf, acc[j], 0, 0, 0);
      }
    }
  }
  float tg = tanhf(p_gate[0]);
  #pragma unroll
  for (int j = 0; j < 8; ++j) {
    int col = j * 16 + rl;
    float bv = b2[col];
    #pragma unroll
    for (int rg = 0; rg < 4; ++rg) {
      int row = rbase + wv * 16 + kg * 4 + rg;
      out[(size_t)row * 128 + col] =
          x[(size_t)row * 128 + col] + tg * (acc[j][rg] + bv);
    }
  }
}

extern "C" void kernel_launch(void* const* d_in, const int* in_sizes, int n_in,
                              void* d_out, int out_size, void* d_ws, size_t ws_size,
                              hipStream_t stream) {
  (void)in_sizes; (void)n_in; (void)out_size; (void)ws_size;
  const float* x = (const float*)d_in[0];
  const float* ln_g = (const float*)d_in[1];
  const float* ln_b = (const float*)d_in[2];
  const float* w1 = (const float*)d_in[3];
  const float* b1 = (const float*)d_in[4];
  const float* w2 = (const float*)d_in[5];
  const float* b2 = (const float*)d_in[6];
  const float* p_log_tau = (const float*)d_in[7];
  const float* p_gate = (const float*)d_in[8];
  float* out = (float*)d_out;

  char* ws = (char*)d_ws;
  size_t off = 0;
  auto alloc = [&](size_t bytes) -> void* {
    off = (off + 255) & ~(size_t)255;
    void* p = ws + off;
    off += bytes;
    return p;
  };
  _Float16* ln16 = (_Float16*)alloc((size_t)NB * NN * 128 * 2);
  _Float16* h16 = (_Float16*)alloc((size_t)NB * NN * 128 * 2);
  _Float16* hn16 = (_Float16*)alloc((size_t)NB * NN * 128 * 2);
  _Float16* T116 = (_Float16*)alloc((size_t)NB * NN * 128 * 2);
  _Float16* T216 = (_Float16*)alloc((size_t)NB * NN * 128 * 2);
  _Float16* w1t16 = (_Float16*)alloc((size_t)128 * 128 * 2);
  _Float16* w2t16 = (_Float16*)alloc((size_t)128 * 384 * 2);
  int* nidx = (int*)alloc((size_t)NB * NN * 32 * 4);
  float* nval = (float*)alloc((size_t)NB * NN * 32 * 4);
  float* dm12 = (float*)alloc((size_t)NB * NN * 4);

  k_prep<<<128, 128, 0, stream>>>(w1, w1t16);
  k_prep2<<<128, 128, 0, stream>>>(w2, w2t16);
  k0_ln<<<NB * NN / 4, 256, 0, stream>>>(x, ln_g, ln_b, ln16);
  k1_mfma<<<NB * NN / 64, 256, 0, stream>>>(ln16, w1t16, b1, h16, hn16);
  k_scores_topk<<<NB * (NN / 64), 256, 0, stream>>>(hn16, nidx, nval, dm12, p_log_tau);
  k_cheb1<<<NB * NN, 128, 0, stream>>>(h16, nidx, nval, dm12, p_log_tau, T116);
  k_cheb2<<<NB * NN, 128, 0, stream>>>(h16, T116, nidx, nval, dm12, p_log_tau, T216);
  k_out<<<NB * NN / 64, 256, 0, stream>>>(x, h16, T116, T216, w2t16, b2, p_gate, out);
}